// Round 2
// baseline (385.558 us; speedup 1.0000x reference)
//
#include <hip/hip_runtime.h>
#include <hip/hip_bf16.h>

typedef unsigned short u16;
typedef __bf16 bf16x8 __attribute__((ext_vector_type(8)));
typedef float floatx4 __attribute__((ext_vector_type(4)));
typedef unsigned short ushort8 __attribute__((ext_vector_type(8)));

#define GLOBAL_AS(p) ((const __attribute__((address_space(1))) void*)(p))
#define LDS_AS(p) ((__attribute__((address_space(3))) void*)(p))

constexpr int NB = 8192;
constexpr int DIN = 512;
constexpr int DH = 2048;
constexpr int DOUT = 512;
constexpr int NEXP = 8;
constexpr int ROWCAP = NB + NEXP * 128;  // 128-padded segments
constexpr int TILE = 8192;               // elements in a 128x64 bf16 tile

__device__ __forceinline__ u16 f2bf(float f) {
    unsigned u = __builtin_bit_cast(unsigned, f);
    unsigned r = u + 0x7FFFu + ((u >> 16) & 1u);
    return (u16)(r >> 16);
}

// element offset within a 128x64 tile for (row, klocal), xor-swizzled 16B chunks
__device__ __forceinline__ int slot_off(int row, int kl) {
    return row * 64 + ((((kl >> 3) ^ (row & 7)) << 3) | (kl & 7));
}

// ---------------- routing: one single-block kernel, per-wave sub-counters ----------------
__global__ void route_kernel(const int* __restrict__ groups, int* __restrict__ cnt,
                             int* __restrict__ offs, int* __restrict__ perm,
                             int* __restrict__ rpos) {
    __shared__ int wc[NEXP * 4];    // [e][wave] counts
    __shared__ int lcur[NEXP * 4];  // running positions
    int t = threadIdx.x;
    int w = t >> 6;
    if (t < NEXP * 4) wc[t] = 0;
    __syncthreads();
    for (int i = t; i < NB; i += 256) atomicAdd(&wc[groups[i] * 4 + w], 1);
    __syncthreads();
    if (t == 0) {
        int run = 0;
        for (int e = 0; e < NEXP; ++e) {
            offs[e] = run;
            int s = run;
            for (int j = 0; j < 4; ++j) { lcur[e * 4 + j] = s; s += wc[e * 4 + j]; }
            cnt[e] = s - run;
            run += (((s - run) + 127) >> 7) << 7;   // 128-aligned segments
        }
    }
    __syncthreads();
    for (int i = t; i < NB; i += 256) {
        int e = groups[i];
        int pos = atomicAdd(&lcur[e * 4 + w], 1);
        perm[pos] = i;
        rpos[i] = pos;
    }
}

// ---------------- fused wide prep: W1/W2 transpose+tile | gather-x ----------------
// grid.x = 4096 (weights) + 2048 (gather) = 6144
__global__ __launch_bounds__(256) void prep_kernel(
        const float* __restrict__ x, const float* __restrict__ W1,
        const float* __restrict__ W2, const int* __restrict__ rpos,
        u16* __restrict__ xsT, u16* __restrict__ w1tT, u16* __restrict__ w2tT) {
    int bx = blockIdx.x;
    int t = threadIdx.x;
    if (bx < 4096) {
        // weight transpose+convert+tile: src [E][K][N] -> tiled [e][nt][kt][128][64]
        __shared__ float tile[64][65];
        bool isW1 = bx < 2048;
        int b = isW1 ? bx : bx - 2048;
        int e = b >> 8;
        int q = b & 255;
        int C = isW1 ? DH : DOUT;                 // N-dim
        int NTP = C >> 7;                         // n-tiles (16 / 4)
        int KTP = isW1 ? (DIN >> 6) : (DH >> 6);  // k-tiles (8 / 32)
        int rt = isW1 ? (q >> 5) : (q >> 3);      // k 64-tile idx
        int ct = isW1 ? (q & 31) : (q & 7);       // n 64-tile idx
        const float* s = (isW1 ? W1 : W2) + (size_t)e * (isW1 ? DIN * DH : DH * DOUT);
        u16* d = isW1 ? w1tT : w2tT;
        int r0 = rt * 64, c0 = ct * 64;
        for (int i = 0; i < 4; ++i) {
            int r = (t >> 4) + i * 16;
            int c = (t & 15) * 4;
            const float4 v = *(const float4*)&s[(size_t)(r0 + r) * C + c0 + c];
            tile[r][c] = v.x; tile[r][c + 1] = v.y; tile[r][c + 2] = v.z; tile[r][c + 3] = v.w;
        }
        __syncthreads();
        for (int i = 0; i < 4; ++i) {
            int c = (t >> 4) + i * 16;    // n-local
            int r = (t & 15) * 4;         // k-local, 4 consecutive
            int n = c0 + c, k = r0 + r;
            ushort4 o;
            o.x = f2bf(tile[r][c]); o.y = f2bf(tile[r + 1][c]);
            o.z = f2bf(tile[r + 2][c]); o.w = f2bf(tile[r + 3][c]);
            size_t off = ((size_t)(e * NTP + (n >> 7)) * KTP + (k >> 6)) * TILE
                         + slot_off(n & 127, k & 63);
            *(ushort4*)&d[off] = o;
        }
    } else {
        // gather-x: 4 rows per block, 64 lanes per row, 8 elems/lane
        int r = t >> 6, lane = t & 63;
        int i = (bx - 4096) * 4 + r;
        int pos = rpos[i];
        int k = lane * 8;
        const float4 a = *(const float4*)&x[(size_t)i * DIN + k];
        const float4 b = *(const float4*)&x[(size_t)i * DIN + k + 4];
        ushort8 o;
        o[0] = f2bf(a.x); o[1] = f2bf(a.y); o[2] = f2bf(a.z); o[3] = f2bf(a.w);
        o[4] = f2bf(b.x); o[5] = f2bf(b.y); o[6] = f2bf(b.z); o[7] = f2bf(b.w);
        int lp = pos & 127;
        size_t off = (size_t)(pos >> 7) * 8 * TILE + (size_t)(k >> 6) * TILE
                     + slot_off(lp, k & 63);
        *(ushort8*)&xsT[off] = o;
    }
}

// ---------------- 256x256 8-phase GEMM core (T3+T4+T5) ----------------
// 512 threads = 8 waves (2M x 4N), per-wave output 128x64 = acc[8][4].
// LDS = 2 K-tile buffers x 4 slots (A0,A1,B0,B1) x 16KB = 128KB.
// Per K-tile, 4 phases (quad qd covers fm {2qd,2qd+1}); B held in regs after qd0.
// Stage schedule (1 half-tile = 16KB = 2 gload_lds/thread per phase):
//   qd0 -> A0[kt+1] (other buf; its last read ended at kt-1 qd3's end barrier)
//   qd1 -> A1[kt+1]
//   qd2 -> B0[kt+2] (same buf; B was consumed into regs at qd0, barrier-separated)
//   qd3 -> B1[kt+2], then s_waitcnt vmcnt(4): leaves exactly the 2 newest
//          half-tiles (B[kt+2]) in flight, guarantees A[kt+1]+B[kt+1] landed.
// Never drains to 0 in steady state (T4); vmcnt(0) only at the kt=KT-2 boundary.
template <int KT>
__device__ __forceinline__ void gemm_core(const u16* tA0, const u16* tA1,
                                          const u16* tB0, const u16* tB1,
                                          u16* sm, floatx4 acc[8][4], int tid) {
    const u16* tb[4] = {tA0, tA1, tB0, tB1};
    int w = tid >> 6, l = tid & 63;
    int q = l >> 4, li = l & 15;
    int wm = w >> 2, wn = w & 3;
    auto stage = [&](int buf, int slot, const u16* g) {
        u16* dst = sm + (size_t)(buf * 4 + slot) * TILE;
        __builtin_amdgcn_global_load_lds(GLOBAL_AS(g + (size_t)tid * 8),
                                         LDS_AS(dst + w * 64 * 8), 16, 0, 0);
        __builtin_amdgcn_global_load_lds(GLOBAL_AS(g + (size_t)(512 + tid) * 8),
                                         LDS_AS(dst + (512 + w * 64) * 8), 16, 0, 0);
    };
    // prologue in steady-state issue order: B[0], A[0], B[1]; vmcnt(4) leaves B[1] in flight
    stage(0, 2, tb[2]); stage(0, 3, tb[3]);
    stage(0, 0, tb[0]); stage(0, 1, tb[1]);
    stage(1, 2, tb[2] + TILE); stage(1, 3, tb[3] + TILE);
    asm volatile("s_waitcnt vmcnt(4)" ::: "memory");
    __builtin_amdgcn_s_barrier();

    int cur = 0;
#pragma unroll 1
    for (int kt = 0; kt < KT; ++kt) {
        const u16* At = sm + (size_t)(cur * 4 + wm) * TILE;
        const u16* Bt = sm + (size_t)(cur * 4 + 2 + (wn >> 1)) * TILE;
        int nrb = (wn & 1) * 64;
        bf16x8 bq[4][2];
#pragma unroll
        for (int qd = 0; qd < 4; ++qd) {
            if (qd == 0) {
#pragma unroll
                for (int fn = 0; fn < 4; ++fn)
#pragma unroll
                    for (int ks = 0; ks < 2; ++ks) {
                        int nr = nrb + fn * 16 + li;
                        int c0 = ks * 4 + q;
                        bq[fn][ks] = *(const bf16x8*)&Bt[nr * 64 + ((c0 ^ (nr & 7)) << 3)];
                    }
            }
            bf16x8 af[2][2];
#pragma unroll
            for (int f2 = 0; f2 < 2; ++f2)
#pragma unroll
                for (int ks = 0; ks < 2; ++ks) {
                    int mr = (qd * 2 + f2) * 16 + li;
                    int c0 = ks * 4 + q;
                    af[f2][ks] = *(const bf16x8*)&At[mr * 64 + ((c0 ^ (mr & 7)) << 3)];
                }
            if (qd == 0 && kt + 1 < KT) stage(cur ^ 1, 0, tb[0] + (size_t)(kt + 1) * TILE);
            if (qd == 1 && kt + 1 < KT) stage(cur ^ 1, 1, tb[1] + (size_t)(kt + 1) * TILE);
            if (qd == 2 && kt + 2 < KT) stage(cur, 2, tb[2] + (size_t)(kt + 2) * TILE);
            if (qd == 3) {
                if (kt + 2 < KT) stage(cur, 3, tb[3] + (size_t)(kt + 2) * TILE);
                if (kt < KT - 2) { asm volatile("s_waitcnt vmcnt(4)" ::: "memory"); }
                else             { asm volatile("s_waitcnt vmcnt(0)" ::: "memory"); }
            }
            __builtin_amdgcn_s_barrier();
            asm volatile("s_waitcnt lgkmcnt(0)" ::: "memory");
            __builtin_amdgcn_sched_barrier(0);
            __builtin_amdgcn_s_setprio(1);
#pragma unroll
            for (int f2 = 0; f2 < 2; ++f2)
#pragma unroll
                for (int fn = 0; fn < 4; ++fn)
#pragma unroll
                    for (int ks = 0; ks < 2; ++ks)
                        acc[qd * 2 + f2][fn] = __builtin_amdgcn_mfma_f32_16x16x32_bf16(
                            af[f2][ks], bq[fn][ks], acc[qd * 2 + f2][fn], 0, 0, 0);
            __builtin_amdgcn_s_setprio(0);
            __builtin_amdgcn_s_barrier();
        }
        cur ^= 1;
    }
}

// ---------------- pass A: h = relu(x @ W1 + b1), bf16 tiled out ----------------
// grid = 8 experts x 8 n256-tiles x 4 m256-tiles = 256, e = bx&7 (XCD affinity)
__global__ __launch_bounds__(512, 2) void gemm_a(
        const u16* __restrict__ At, const u16* __restrict__ Bt,
        const float* __restrict__ bias, u16* __restrict__ hsT,
        const int* __restrict__ cnt, const int* __restrict__ offs) {
    __shared__ u16 sm[2 * 4 * TILE];   // 128 KiB
    int bx = blockIdx.x;
    int e = bx & 7;
    int r = bx >> 3;
    int nt = r & 7;
    int mt0 = r >> 3;
    int count = cnt[e];
    int base128 = offs[e] >> 7;
    int tid = threadIdx.x;
    int w = tid >> 6, l = tid & 63, q = l >> 4, li = l & 15;
    int wm = w >> 2, wn = w & 3;
#pragma unroll 1
    for (int mt = mt0; mt * 256 < count; mt += 4) {
        const u16* a0 = At + (size_t)((base128 + mt * 2 + 0) * 8) * TILE;
        const u16* a1 = At + (size_t)((base128 + mt * 2 + 1) * 8) * TILE;
        const u16* b0 = Bt + (size_t)((e * 16 + nt * 2 + 0) * 8) * TILE;
        const u16* b1 = Bt + (size_t)((e * 16 + nt * 2 + 1) * 8) * TILE;
        floatx4 acc[8][4];
#pragma unroll
        for (int a = 0; a < 8; ++a)
#pragma unroll
            for (int b = 0; b < 4; ++b) acc[a][b] = (floatx4)0.0f;
        gemm_core<8>(a0, a1, b0, b1, sm, acc, tid);

        // epilogue: each wave owns exactly one 128x64 hsT tile
        // (rows = wm-half of 256-block, cols = wn 64-group); build swizzled image
        // in its private 16KB LDS region, then dump fully-contiguous.
        float bv[4];
#pragma unroll
        for (int fn = 0; fn < 4; ++fn)
            bv[fn] = bias[(size_t)e * DH + nt * 256 + wn * 64 + fn * 16 + li];
        u16* img = sm + (size_t)w * TILE;
#pragma unroll
        for (int fm = 0; fm < 8; ++fm)
#pragma unroll
            for (int fn = 0; fn < 4; ++fn)
#pragma unroll
                for (int rr = 0; rr < 4; ++rr) {
                    float v = acc[fm][fn][rr] + bv[fn];
                    v = v > 0.0f ? v : 0.0f;
                    img[slot_off(fm * 16 + q * 4 + rr, fn * 16 + li)] = f2bf(v);
                }
        __syncthreads();
        int t128 = mt * 2 + wm;
        if (t128 * 128 < count) {   // guard: don't write past this expert's segment
            u16* dst = hsT + ((size_t)(base128 + t128) * 32 + nt * 4 + wn) * TILE;
#pragma unroll
            for (int j = 0; j < 16; ++j)
                *(ushort8*)&dst[j * 512 + l * 8] = *(const ushort8*)&img[j * 512 + l * 8];
        }
        __syncthreads();   // LDS safe for next m-tile's prologue
    }
}

// ---------------- pass B: partial[ks] = h @ W2 over K-half, fp32 sorted layout ----------
// grid = 8 experts x 2 n256-tiles x 2 k-splits x 4 m256-tiles = 128
__global__ __launch_bounds__(512, 2) void gemm_b(
        const u16* __restrict__ At, const u16* __restrict__ Bt,
        float* __restrict__ ps, const int* __restrict__ cnt,
        const int* __restrict__ offs) {
    __shared__ u16 sm[2 * 4 * TILE];   // 128 KiB
    int bx = blockIdx.x;
    int e = bx & 7;
    int r = bx >> 3;
    int nt = r & 1;
    int ks = (r >> 1) & 1;
    int mt0 = r >> 2;
    int count = cnt[e];
    int seg = offs[e];
    int base128 = seg >> 7;
    int tid = threadIdx.x;
    int w = tid >> 6, l = tid & 63, q = l >> 4, li = l & 15;
    int wm = w >> 2, wn = w & 3;
#pragma unroll 1
    for (int mt = mt0; mt * 256 < count; mt += 4) {
        const u16* a0 = At + (size_t)((base128 + mt * 2 + 0) * 32 + ks * 16) * TILE;
        const u16* a1 = At + (size_t)((base128 + mt * 2 + 1) * 32 + ks * 16) * TILE;
        const u16* b0 = Bt + (size_t)((e * 4 + nt * 2 + 0) * 32 + ks * 16) * TILE;
        const u16* b1 = Bt + (size_t)((e * 4 + nt * 2 + 1) * 32 + ks * 16) * TILE;
        floatx4 acc[8][4];
#pragma unroll
        for (int a = 0; a < 8; ++a)
#pragma unroll
            for (int b = 0; b < 4; ++b) acc[a][b] = (floatx4)0.0f;
        gemm_core<16>(a0, a1, b0, b1, sm, acc, tid);

        // direct fp32 stores; guard second m128-half against segment overflow
        int t128 = mt * 2 + wm;
        if (t128 * 128 < count) {
            float* pbase = ps + ((size_t)ks * ROWCAP + seg + (size_t)mt * 256) * DOUT;
#pragma unroll
            for (int fn = 0; fn < 4; ++fn) {
                int col = nt * 256 + wn * 64 + fn * 16 + li;
#pragma unroll
                for (int fm = 0; fm < 8; ++fm) {
                    int row0 = wm * 128 + fm * 16 + q * 4;
#pragma unroll
                    for (int rr = 0; rr < 4; ++rr)
                        pbase[(size_t)(row0 + rr) * DOUT + col] = acc[fm][fn][rr];
                }
            }
        }
        // no barrier needed: next prologue only touches LDS, all waves already
        // passed the core's final phase barrier (global stores don't alias LDS)
    }
}

// ---------------- reduce: out[i] = ps[0][rpos[i]] + ps[1][rpos[i]] + b2[groups[i]] ------
__global__ __launch_bounds__(256) void reduce_b(
        const float* __restrict__ ps, const int* __restrict__ rpos,
        const int* __restrict__ groups, const float* __restrict__ b2,
        float* __restrict__ out) {
    int idx = blockIdx.x * 256 + threadIdx.x;
    int i = idx >> 7;
    int c = (idx & 127) * 4;
    int pos = rpos[i];
    int g = groups[i];
    const float4 v0 = *(const float4*)&ps[(size_t)pos * DOUT + c];
    const float4 v1 = *(const float4*)&ps[((size_t)ROWCAP + pos) * DOUT + c];
    const float4 bb = *(const float4*)&b2[(size_t)g * DOUT + c];
    float4 o;
    o.x = v0.x + v1.x + bb.x; o.y = v0.y + v1.y + bb.y;
    o.z = v0.z + v1.z + bb.z; o.w = v0.w + v1.w + bb.w;
    *(float4*)&out[(size_t)i * DOUT + c] = o;
}

// ---------------- launch ----------------
extern "C" void kernel_launch(void* const* d_in, const int* in_sizes, int n_in,
                              void* d_out, int out_size, void* d_ws, size_t ws_size,
                              hipStream_t stream) {
    const float* x = (const float*)d_in[0];
    const int* groups = (const int*)d_in[1];
    const float* W1 = (const float*)d_in[2];
    const float* b1 = (const float*)d_in[3];
    const float* W2 = (const float*)d_in[4];
    const float* b2 = (const float*)d_in[5];
    float* out = (float*)d_out;

    char* ws = (char*)d_ws;
    size_t o = 0;
    auto alloc = [&](size_t bytes) {
        void* p = ws + o;
        o = (o + bytes + 255) & ~(size_t)255;
        return p;
    };
    int* cnt = (int*)alloc(NEXP * 4);
    int* offs = (int*)alloc(NEXP * 4);
    int* perm = (int*)alloc((size_t)ROWCAP * 4);
    int* rpos = (int*)alloc((size_t)NB * 4);
    u16* xsT = (u16*)alloc((size_t)(ROWCAP / 128) * 8 * TILE * 2);    // ~9.4 MB
    u16* w1tT = (u16*)alloc((size_t)NEXP * DIN * DH * 2);             // 16.8 MB
    u16* w2tT = (u16*)alloc((size_t)NEXP * DH * DOUT * 2);            // 16.8 MB
    u16* hsT = (u16*)alloc((size_t)(ROWCAP / 128) * 32 * TILE * 2);   // ~37.7 MB
    float* ps = (float*)alloc((size_t)2 * ROWCAP * DOUT * 4);         // ~37.7 MB

    route_kernel<<<1, 256, 0, stream>>>(groups, cnt, offs, perm, rpos);
    prep_kernel<<<6144, 256, 0, stream>>>(x, W1, W2, rpos, xsT, w1tT, w2tT);
    gemm_a<<<256, 512, 0, stream>>>(xsT, w1tT, b1, hsT, cnt, offs);
    gemm_b<<<128, 512, 0, stream>>>(hsT, w2tT, ps, cnt, offs);
    reduce_b<<<(NB * (DOUT / 4)) / 256, 256, 0, stream>>>(ps, rpos, groups, b2, out);
}

// Round 3
// 385.176 us; speedup vs baseline: 1.0010x; 1.0010x over previous
//
#include <hip/hip_runtime.h>
#include <hip/hip_bf16.h>

typedef unsigned short u16;
typedef __bf16 bf16x8 __attribute__((ext_vector_type(8)));
typedef float floatx4 __attribute__((ext_vector_type(4)));
typedef unsigned short ushort8 __attribute__((ext_vector_type(8)));

#define GLOBAL_AS(p) ((const __attribute__((address_space(1))) void*)(p))
#define LDS_AS(p) ((__attribute__((address_space(3))) void*)(p))

constexpr int NB = 8192;
constexpr int DIN = 512;
constexpr int DH = 2048;
constexpr int DOUT = 512;
constexpr int NEXP = 8;
constexpr int ROWCAP = NB + NEXP * 128;  // 128-padded segments
constexpr int TILE = 8192;               // elements in a 128x64 bf16 tile

__device__ __forceinline__ u16 f2bf(float f) {
    unsigned u = __builtin_bit_cast(unsigned, f);
    unsigned r = u + 0x7FFFu + ((u >> 16) & 1u);
    return (u16)(r >> 16);
}

// element offset within a 128x64 tile for (row, klocal), xor-swizzled 16B chunks
__device__ __forceinline__ int slot_off(int row, int kl) {
    return row * 64 + ((((kl >> 3) ^ (row & 7)) << 3) | (kl & 7));
}

// ---------------- routing: one single-block kernel, per-wave sub-counters ----------------
__global__ void route_kernel(const int* __restrict__ groups, int* __restrict__ cnt,
                             int* __restrict__ offs, int* __restrict__ perm,
                             int* __restrict__ rpos) {
    __shared__ int wc[NEXP * 4];    // [e][wave] counts
    __shared__ int lcur[NEXP * 4];  // running positions
    int t = threadIdx.x;
    int w = t >> 6;
    if (t < NEXP * 4) wc[t] = 0;
    __syncthreads();
    for (int i = t; i < NB; i += 256) atomicAdd(&wc[groups[i] * 4 + w], 1);
    __syncthreads();
    if (t == 0) {
        int run = 0;
        for (int e = 0; e < NEXP; ++e) {
            offs[e] = run;
            int s = run;
            for (int j = 0; j < 4; ++j) { lcur[e * 4 + j] = s; s += wc[e * 4 + j]; }
            cnt[e] = s - run;
            run += (((s - run) + 127) >> 7) << 7;   // 128-aligned segments
        }
    }
    __syncthreads();
    for (int i = t; i < NB; i += 256) {
        int e = groups[i];
        int pos = atomicAdd(&lcur[e * 4 + w], 1);
        perm[pos] = i;
        rpos[i] = pos;
    }
}

// ---------------- fused wide prep: W1/W2 transpose+tile | gather-x ----------------
// grid.x = 4096 (weights) + 2048 (gather) = 6144
__global__ __launch_bounds__(256) void prep_kernel(
        const float* __restrict__ x, const float* __restrict__ W1,
        const float* __restrict__ W2, const int* __restrict__ rpos,
        u16* __restrict__ xsT, u16* __restrict__ w1tT, u16* __restrict__ w2tT) {
    int bx = blockIdx.x;
    int t = threadIdx.x;
    if (bx < 4096) {
        // weight transpose+convert+tile: src [E][K][N] -> tiled [e][nt][kt][128][64]
        __shared__ float tile[64][65];
        bool isW1 = bx < 2048;
        int b = isW1 ? bx : bx - 2048;
        int e = b >> 8;
        int q = b & 255;
        int C = isW1 ? DH : DOUT;                 // N-dim
        int NTP = C >> 7;                         // n-tiles (16 / 4)
        int KTP = isW1 ? (DIN >> 6) : (DH >> 6);  // k-tiles (8 / 32)
        int rt = isW1 ? (q >> 5) : (q >> 3);      // k 64-tile idx
        int ct = isW1 ? (q & 31) : (q & 7);       // n 64-tile idx
        const float* s = (isW1 ? W1 : W2) + (size_t)e * (isW1 ? DIN * DH : DH * DOUT);
        u16* d = isW1 ? w1tT : w2tT;
        int r0 = rt * 64, c0 = ct * 64;
        for (int i = 0; i < 4; ++i) {
            int r = (t >> 4) + i * 16;
            int c = (t & 15) * 4;
            const float4 v = *(const float4*)&s[(size_t)(r0 + r) * C + c0 + c];
            tile[r][c] = v.x; tile[r][c + 1] = v.y; tile[r][c + 2] = v.z; tile[r][c + 3] = v.w;
        }
        __syncthreads();
        for (int i = 0; i < 4; ++i) {
            int c = (t >> 4) + i * 16;    // n-local
            int r = (t & 15) * 4;         // k-local, 4 consecutive
            int n = c0 + c, k = r0 + r;
            ushort4 o;
            o.x = f2bf(tile[r][c]); o.y = f2bf(tile[r + 1][c]);
            o.z = f2bf(tile[r + 2][c]); o.w = f2bf(tile[r + 3][c]);
            size_t off = ((size_t)(e * NTP + (n >> 7)) * KTP + (k >> 6)) * TILE
                         + slot_off(n & 127, k & 63);
            *(ushort4*)&d[off] = o;
        }
    } else {
        // gather-x: 4 rows per block, 64 lanes per row, 8 elems/lane
        int r = t >> 6, lane = t & 63;
        int i = (bx - 4096) * 4 + r;
        int pos = rpos[i];
        int k = lane * 8;
        const float4 a = *(const float4*)&x[(size_t)i * DIN + k];
        const float4 b = *(const float4*)&x[(size_t)i * DIN + k + 4];
        ushort8 o;
        o[0] = f2bf(a.x); o[1] = f2bf(a.y); o[2] = f2bf(a.z); o[3] = f2bf(a.w);
        o[4] = f2bf(b.x); o[5] = f2bf(b.y); o[6] = f2bf(b.z); o[7] = f2bf(b.w);
        int lp = pos & 127;
        size_t off = (size_t)(pos >> 7) * 8 * TILE + (size_t)(k >> 6) * TILE
                     + slot_off(lp, k & 63);
        *(ushort8*)&xsT[off] = o;
    }
}

// ---------------- 256x256 8-phase GEMM core (T3+T4+T5) ----------------
// 512 threads = 8 waves (2M x 4N), per-wave output 128x64 = acc[8][4].
// LDS = 2 K-tile buffers x 4 slots (A0,A1,B0,B1) x 16KB = 128KB.
// Per K-tile, 4 phases (quad qd covers fm {2qd,2qd+1}); B held in regs after qd0.
// Stage schedule (1 half-tile = 16KB = 2 gload_lds/thread per phase):
//   qd0 -> A0[kt+1] (other buf; its last read ended at kt-1 qd3's end barrier)
//   qd1 -> A1[kt+1]
//   qd2 -> B0[kt+2] (same buf; B was consumed into regs at qd0, barrier-separated)
//   qd3 -> B1[kt+2], then s_waitcnt vmcnt(4): leaves exactly the 2 newest
//          half-tiles (B[kt+2]) in flight, guarantees A[kt+1]+B[kt+1] landed.
// Never drains to 0 in steady state (T4); vmcnt(0) only at the kt=KT-2 boundary.
template <int KT>
__device__ __forceinline__ void gemm_core(const u16* tA0, const u16* tA1,
                                          const u16* tB0, const u16* tB1,
                                          u16* sm, floatx4 acc[8][4], int tid) {
    const u16* tb[4] = {tA0, tA1, tB0, tB1};
    int w = tid >> 6, l = tid & 63;
    int q = l >> 4, li = l & 15;
    int wm = w >> 2, wn = w & 3;
    auto stage = [&](int buf, int slot, const u16* g) {
        u16* dst = sm + (size_t)(buf * 4 + slot) * TILE;
        __builtin_amdgcn_global_load_lds(GLOBAL_AS(g + (size_t)tid * 8),
                                         LDS_AS(dst + w * 64 * 8), 16, 0, 0);
        __builtin_amdgcn_global_load_lds(GLOBAL_AS(g + (size_t)(512 + tid) * 8),
                                         LDS_AS(dst + (512 + w * 64) * 8), 16, 0, 0);
    };
    // prologue in steady-state issue order: B[0], A[0], B[1]; vmcnt(4) leaves B[1] in flight
    stage(0, 2, tb[2]); stage(0, 3, tb[3]);
    stage(0, 0, tb[0]); stage(0, 1, tb[1]);
    stage(1, 2, tb[2] + TILE); stage(1, 3, tb[3] + TILE);
    asm volatile("s_waitcnt vmcnt(4)" ::: "memory");
    __builtin_amdgcn_s_barrier();

    int cur = 0;
#pragma unroll 1
    for (int kt = 0; kt < KT; ++kt) {
        const u16* At = sm + (size_t)(cur * 4 + wm) * TILE;
        const u16* Bt = sm + (size_t)(cur * 4 + 2 + (wn >> 1)) * TILE;
        int nrb = (wn & 1) * 64;
        bf16x8 bq[4][2];
#pragma unroll
        for (int qd = 0; qd < 4; ++qd) {
            if (qd == 0) {
#pragma unroll
                for (int fn = 0; fn < 4; ++fn)
#pragma unroll
                    for (int ks = 0; ks < 2; ++ks) {
                        int nr = nrb + fn * 16 + li;
                        int c0 = ks * 4 + q;
                        bq[fn][ks] = *(const bf16x8*)&Bt[nr * 64 + ((c0 ^ (nr & 7)) << 3)];
                    }
            }
            bf16x8 af[2][2];
#pragma unroll
            for (int f2 = 0; f2 < 2; ++f2)
#pragma unroll
                for (int ks = 0; ks < 2; ++ks) {
                    int mr = (qd * 2 + f2) * 16 + li;
                    int c0 = ks * 4 + q;
                    af[f2][ks] = *(const bf16x8*)&At[mr * 64 + ((c0 ^ (mr & 7)) << 3)];
                }
            if (qd == 0 && kt + 1 < KT) stage(cur ^ 1, 0, tb[0] + (size_t)(kt + 1) * TILE);
            if (qd == 1 && kt + 1 < KT) stage(cur ^ 1, 1, tb[1] + (size_t)(kt + 1) * TILE);
            if (qd == 2 && kt + 2 < KT) stage(cur, 2, tb[2] + (size_t)(kt + 2) * TILE);
            if (qd == 3) {
                if (kt + 2 < KT) stage(cur, 3, tb[3] + (size_t)(kt + 2) * TILE);
                if (kt < KT - 2) { asm volatile("s_waitcnt vmcnt(4)" ::: "memory"); }
                else             { asm volatile("s_waitcnt vmcnt(0)" ::: "memory"); }
            }
            __builtin_amdgcn_s_barrier();
            asm volatile("s_waitcnt lgkmcnt(0)" ::: "memory");
            __builtin_amdgcn_sched_barrier(0);
            __builtin_amdgcn_s_setprio(1);
#pragma unroll
            for (int f2 = 0; f2 < 2; ++f2)
#pragma unroll
                for (int fn = 0; fn < 4; ++fn)
#pragma unroll
                    for (int ks = 0; ks < 2; ++ks)
                        acc[qd * 2 + f2][fn] = __builtin_amdgcn_mfma_f32_16x16x32_bf16(
                            af[f2][ks], bq[fn][ks], acc[qd * 2 + f2][fn], 0, 0, 0);
            __builtin_amdgcn_s_setprio(0);
            __builtin_amdgcn_s_barrier();
        }
        cur ^= 1;
    }
}

// ---------------- pass A: h = relu(x @ W1 + b1), bf16 tiled out ----------------
// grid = 8 experts x 8 n256-tiles x 4 m256-tiles = 256, e = bx&7 (XCD affinity)
// __launch_bounds__(512, 1): second arg is MIN BLOCKS/CU (CUDA semantics on this
// toolchain — round-2 evidence: arg=2 capped VGPR at 128 and spilled the whole
// 128-VGPR accumulator, WRITE_SIZE 91.6MB vs 37.7 needed, MfmaUtil 0.15%).
// With 1 block/CU the 8-wave block caps allocation at 256 VGPR (2 waves/EU
// residency requirement), which is the budget this template is designed for.
__global__ __launch_bounds__(512, 1) void gemm_a(
        const u16* __restrict__ At, const u16* __restrict__ Bt,
        const float* __restrict__ bias, u16* __restrict__ hsT,
        const int* __restrict__ cnt, const int* __restrict__ offs) {
    __shared__ u16 sm[2 * 4 * TILE];   // 128 KiB
    int bx = blockIdx.x;
    int e = bx & 7;
    int r = bx >> 3;
    int nt = r & 7;
    int mt0 = r >> 3;
    int count = cnt[e];
    int base128 = offs[e] >> 7;
    int tid = threadIdx.x;
    int w = tid >> 6, l = tid & 63, q = l >> 4, li = l & 15;
    int wm = w >> 2, wn = w & 3;
#pragma unroll 1
    for (int mt = mt0; mt * 256 < count; mt += 4) {
        const u16* a0 = At + (size_t)((base128 + mt * 2 + 0) * 8) * TILE;
        const u16* a1 = At + (size_t)((base128 + mt * 2 + 1) * 8) * TILE;
        const u16* b0 = Bt + (size_t)((e * 16 + nt * 2 + 0) * 8) * TILE;
        const u16* b1 = Bt + (size_t)((e * 16 + nt * 2 + 1) * 8) * TILE;
        floatx4 acc[8][4];
#pragma unroll
        for (int a = 0; a < 8; ++a)
#pragma unroll
            for (int b = 0; b < 4; ++b) acc[a][b] = (floatx4)0.0f;
        gemm_core<8>(a0, a1, b0, b1, sm, acc, tid);

        // epilogue: each wave owns exactly one 128x64 hsT tile
        // (rows = wm-half of 256-block, cols = wn 64-group); build swizzled image
        // in its private 16KB LDS region, then dump fully-contiguous.
        float bv[4];
#pragma unroll
        for (int fn = 0; fn < 4; ++fn)
            bv[fn] = bias[(size_t)e * DH + nt * 256 + wn * 64 + fn * 16 + li];
        u16* img = sm + (size_t)w * TILE;
#pragma unroll
        for (int fm = 0; fm < 8; ++fm)
#pragma unroll
            for (int fn = 0; fn < 4; ++fn)
#pragma unroll
                for (int rr = 0; rr < 4; ++rr) {
                    float v = acc[fm][fn][rr] + bv[fn];
                    v = v > 0.0f ? v : 0.0f;
                    img[slot_off(fm * 16 + q * 4 + rr, fn * 16 + li)] = f2bf(v);
                }
        __syncthreads();
        int t128 = mt * 2 + wm;
        if (t128 * 128 < count) {   // guard: don't write past this expert's segment
            u16* dst = hsT + ((size_t)(base128 + t128) * 32 + nt * 4 + wn) * TILE;
#pragma unroll
            for (int j = 0; j < 16; ++j)
                *(ushort8*)&dst[j * 512 + l * 8] = *(const ushort8*)&img[j * 512 + l * 8];
        }
        __syncthreads();   // LDS safe for next m-tile's prologue
    }
}

// ---------------- pass B: partial[ks] = h @ W2 over K-half, fp32 sorted layout ----------
// grid = 8 experts x 2 n256-tiles x 2 k-splits x 4 m256-tiles = 128
__global__ __launch_bounds__(512, 1) void gemm_b(
        const u16* __restrict__ At, const u16* __restrict__ Bt,
        float* __restrict__ ps, const int* __restrict__ cnt,
        const int* __restrict__ offs) {
    __shared__ u16 sm[2 * 4 * TILE];   // 128 KiB
    int bx = blockIdx.x;
    int e = bx & 7;
    int r = bx >> 3;
    int nt = r & 1;
    int ks = (r >> 1) & 1;
    int mt0 = r >> 2;
    int count = cnt[e];
    int seg = offs[e];
    int base128 = seg >> 7;
    int tid = threadIdx.x;
    int w = tid >> 6, l = tid & 63, q = l >> 4, li = l & 15;
    int wm = w >> 2, wn = w & 3;
#pragma unroll 1
    for (int mt = mt0; mt * 256 < count; mt += 4) {
        const u16* a0 = At + (size_t)((base128 + mt * 2 + 0) * 32 + ks * 16) * TILE;
        const u16* a1 = At + (size_t)((base128 + mt * 2 + 1) * 32 + ks * 16) * TILE;
        const u16* b0 = Bt + (size_t)((e * 4 + nt * 2 + 0) * 32 + ks * 16) * TILE;
        const u16* b1 = Bt + (size_t)((e * 4 + nt * 2 + 1) * 32 + ks * 16) * TILE;
        floatx4 acc[8][4];
#pragma unroll
        for (int a = 0; a < 8; ++a)
#pragma unroll
            for (int b = 0; b < 4; ++b) acc[a][b] = (floatx4)0.0f;
        gemm_core<16>(a0, a1, b0, b1, sm, acc, tid);

        // direct fp32 stores; guard second m128-half against segment overflow
        int t128 = mt * 2 + wm;
        if (t128 * 128 < count) {
            float* pbase = ps + ((size_t)ks * ROWCAP + seg + (size_t)mt * 256) * DOUT;
#pragma unroll
            for (int fn = 0; fn < 4; ++fn) {
                int col = nt * 256 + wn * 64 + fn * 16 + li;
#pragma unroll
                for (int fm = 0; fm < 8; ++fm) {
                    int row0 = wm * 128 + fm * 16 + q * 4;
#pragma unroll
                    for (int rr = 0; rr < 4; ++rr)
                        pbase[(size_t)(row0 + rr) * DOUT + col] = acc[fm][fn][rr];
                }
            }
        }
        // no barrier needed: next prologue only touches LDS, all waves already
        // passed the core's final phase barrier (global stores don't alias LDS)
    }
}

// ---------------- reduce: out[i] = ps[0][rpos[i]] + ps[1][rpos[i]] + b2[groups[i]] ------
__global__ __launch_bounds__(256) void reduce_b(
        const float* __restrict__ ps, const int* __restrict__ rpos,
        const int* __restrict__ groups, const float* __restrict__ b2,
        float* __restrict__ out) {
    int idx = blockIdx.x * 256 + threadIdx.x;
    int i = idx >> 7;
    int c = (idx & 127) * 4;
    int pos = rpos[i];
    int g = groups[i];
    const float4 v0 = *(const float4*)&ps[(size_t)pos * DOUT + c];
    const float4 v1 = *(const float4*)&ps[((size_t)ROWCAP + pos) * DOUT + c];
    const float4 bb = *(const float4*)&b2[(size_t)g * DOUT + c];
    float4 o;
    o.x = v0.x + v1.x + bb.x; o.y = v0.y + v1.y + bb.y;
    o.z = v0.z + v1.z + bb.z; o.w = v0.w + v1.w + bb.w;
    *(float4*)&out[(size_t)i * DOUT + c] = o;
}

// ---------------- launch ----------------
extern "C" void kernel_launch(void* const* d_in, const int* in_sizes, int n_in,
                              void* d_out, int out_size, void* d_ws, size_t ws_size,
                              hipStream_t stream) {
    const float* x = (const float*)d_in[0];
    const int* groups = (const int*)d_in[1];
    const float* W1 = (const float*)d_in[2];
    const float* b1 = (const float*)d_in[3];
    const float* W2 = (const float*)d_in[4];
    const float* b2 = (const float*)d_in[5];
    float* out = (float*)d_out;

    char* ws = (char*)d_ws;
    size_t o = 0;
    auto alloc = [&](size_t bytes) {
        void* p = ws + o;
        o = (o + bytes + 255) & ~(size_t)255;
        return p;
    };
    int* cnt = (int*)alloc(NEXP * 4);
    int* offs = (int*)alloc(NEXP * 4);
    int* perm = (int*)alloc((size_t)ROWCAP * 4);
    int* rpos = (int*)alloc((size_t)NB * 4);
    u16* xsT = (u16*)alloc((size_t)(ROWCAP / 128) * 8 * TILE * 2);    // ~9.4 MB
    u16* w1tT = (u16*)alloc((size_t)NEXP * DIN * DH * 2);             // 16.8 MB
    u16* w2tT = (u16*)alloc((size_t)NEXP * DH * DOUT * 2);            // 16.8 MB
    u16* hsT = (u16*)alloc((size_t)(ROWCAP / 128) * 32 * TILE * 2);   // ~37.7 MB
    float* ps = (float*)alloc((size_t)2 * ROWCAP * DOUT * 4);         // ~37.7 MB

    route_kernel<<<1, 256, 0, stream>>>(groups, cnt, offs, perm, rpos);
    prep_kernel<<<6144, 256, 0, stream>>>(x, W1, W2, rpos, xsT, w1tT, w2tT);
    gemm_a<<<256, 512, 0, stream>>>(xsT, w1tT, b1, hsT, cnt, offs);
    gemm_b<<<128, 512, 0, stream>>>(hsT, w2tT, ps, cnt, offs);
    reduce_b<<<(NB * (DOUT / 4)) / 256, 256, 0, stream>>>(ps, rpos, groups, b2, out);
}

// Round 4
// 384.676 us; speedup vs baseline: 1.0023x; 1.0013x over previous
//
#include <hip/hip_runtime.h>
#include <hip/hip_bf16.h>

typedef unsigned short u16;
typedef __bf16 bf16x8 __attribute__((ext_vector_type(8)));
typedef float floatx4 __attribute__((ext_vector_type(4)));
typedef unsigned short ushort8 __attribute__((ext_vector_type(8)));

#define GLOBAL_AS(p) ((const __attribute__((address_space(1))) void*)(p))
#define LDS_AS(p) ((__attribute__((address_space(3))) void*)(p))

constexpr int NB = 8192;
constexpr int DIN = 512;
constexpr int DH = 2048;
constexpr int DOUT = 512;
constexpr int NEXP = 8;
constexpr int ROWCAP = NB + NEXP * 128;  // 128-padded segments
constexpr int TILE = 8192;               // elements in a 128x64 bf16 tile

__device__ __forceinline__ u16 f2bf(float f) {
    unsigned u = __builtin_bit_cast(unsigned, f);
    unsigned r = u + 0x7FFFu + ((u >> 16) & 1u);
    return (u16)(r >> 16);
}

// element offset within a 128x64 tile for (row, klocal), xor-swizzled 16B chunks
__device__ __forceinline__ int slot_off(int row, int kl) {
    return row * 64 + ((((kl >> 3) ^ (row & 7)) << 3) | (kl & 7));
}

// ---------------- routing: one single-block kernel, per-wave sub-counters ----------------
__global__ void route_kernel(const int* __restrict__ groups, int* __restrict__ cnt,
                             int* __restrict__ offs, int* __restrict__ perm,
                             int* __restrict__ rpos) {
    __shared__ int wc[NEXP * 4];    // [e][wave] counts
    __shared__ int lcur[NEXP * 4];  // running positions
    int t = threadIdx.x;
    int w = t >> 6;
    if (t < NEXP * 4) wc[t] = 0;
    __syncthreads();
    for (int i = t; i < NB; i += 256) atomicAdd(&wc[groups[i] * 4 + w], 1);
    __syncthreads();
    if (t == 0) {
        int run = 0;
        for (int e = 0; e < NEXP; ++e) {
            offs[e] = run;
            int s = run;
            for (int j = 0; j < 4; ++j) { lcur[e * 4 + j] = s; s += wc[e * 4 + j]; }
            cnt[e] = s - run;
            run += (((s - run) + 127) >> 7) << 7;   // 128-aligned segments
        }
    }
    __syncthreads();
    for (int i = t; i < NB; i += 256) {
        int e = groups[i];
        int pos = atomicAdd(&lcur[e * 4 + w], 1);
        perm[pos] = i;
        rpos[i] = pos;
    }
}

// ---------------- fused wide prep: W1/W2 transpose+tile | gather-x ----------------
// grid.x = 4096 (weights) + 2048 (gather) = 6144
__global__ __launch_bounds__(256) void prep_kernel(
        const float* __restrict__ x, const float* __restrict__ W1,
        const float* __restrict__ W2, const int* __restrict__ rpos,
        u16* __restrict__ xsT, u16* __restrict__ w1tT, u16* __restrict__ w2tT) {
    int bx = blockIdx.x;
    int t = threadIdx.x;
    if (bx < 4096) {
        // weight transpose+convert+tile: src [E][K][N] -> tiled [e][nt][kt][128][64]
        __shared__ float tile[64][65];
        bool isW1 = bx < 2048;
        int b = isW1 ? bx : bx - 2048;
        int e = b >> 8;
        int q = b & 255;
        int C = isW1 ? DH : DOUT;                 // N-dim
        int NTP = C >> 7;                         // n-tiles (16 / 4)
        int KTP = isW1 ? (DIN >> 6) : (DH >> 6);  // k-tiles (8 / 32)
        int rt = isW1 ? (q >> 5) : (q >> 3);      // k 64-tile idx
        int ct = isW1 ? (q & 31) : (q & 7);       // n 64-tile idx
        const float* s = (isW1 ? W1 : W2) + (size_t)e * (isW1 ? DIN * DH : DH * DOUT);
        u16* d = isW1 ? w1tT : w2tT;
        int r0 = rt * 64, c0 = ct * 64;
        for (int i = 0; i < 4; ++i) {
            int r = (t >> 4) + i * 16;
            int c = (t & 15) * 4;
            const float4 v = *(const float4*)&s[(size_t)(r0 + r) * C + c0 + c];
            tile[r][c] = v.x; tile[r][c + 1] = v.y; tile[r][c + 2] = v.z; tile[r][c + 3] = v.w;
        }
        __syncthreads();
        for (int i = 0; i < 4; ++i) {
            int c = (t >> 4) + i * 16;    // n-local
            int r = (t & 15) * 4;         // k-local, 4 consecutive
            int n = c0 + c, k = r0 + r;
            ushort4 o;
            o.x = f2bf(tile[r][c]); o.y = f2bf(tile[r + 1][c]);
            o.z = f2bf(tile[r + 2][c]); o.w = f2bf(tile[r + 3][c]);
            size_t off = ((size_t)(e * NTP + (n >> 7)) * KTP + (k >> 6)) * TILE
                         + slot_off(n & 127, k & 63);
            *(ushort4*)&d[off] = o;
        }
    } else {
        // gather-x: 4 rows per block, 64 lanes per row, 8 elems/lane
        int r = t >> 6, lane = t & 63;
        int i = (bx - 4096) * 4 + r;
        int pos = rpos[i];
        int k = lane * 8;
        const float4 a = *(const float4*)&x[(size_t)i * DIN + k];
        const float4 b = *(const float4*)&x[(size_t)i * DIN + k + 4];
        ushort8 o;
        o[0] = f2bf(a.x); o[1] = f2bf(a.y); o[2] = f2bf(a.z); o[3] = f2bf(a.w);
        o[4] = f2bf(b.x); o[5] = f2bf(b.y); o[6] = f2bf(b.z); o[7] = f2bf(b.w);
        int lp = pos & 127;
        size_t off = (size_t)(pos >> 7) * 8 * TILE + (size_t)(k >> 6) * TILE
                     + slot_off(lp, k & 63);
        *(ushort8*)&xsT[off] = o;
    }
}

// ---------------- 256x256 8-phase GEMM core (T3+T4+T5) ----------------
// 512 threads = 8 waves (2M x 4N), per-wave output 128x64 = acc[8][4].
// LDS = 2 K-tile buffers x 4 slots (A0,A1,B0,B1) x 16KB = 128KB.
// REGISTER-SAFETY RULES (rounds 2/3 post-mortem: acc spilled to scratch,
// +61MB write traffic, MfmaUtil 5%): acc is reference-to-array (no pointer
// decay / address escape -> SROA promotes to regs); the 4 phases are written
// as explicit blocks with LITERAL indices (no unroll-dependent runtime
// indexing); B-frags are named scalars; waitcnt asm has NO "memory" clobber
// (ordering carried by adjacent convergent s_barrier, as in the proven
// 8-phase template).
// Stage schedule per K-tile kt (1 stage = one full 16KB tile, 2 gload/thread):
//   ph0 -> A0[kt+1] (buf^1)   ph1 -> A1[kt+1] (buf^1)
//   ph2 -> B0[kt+2] (buf)     ph3 -> B1[kt+2] (buf), then vmcnt(4):
//   drains B[kt+1] + A[kt+1] (oldest 8), leaves B[kt+2] (newest 4) in flight.
// Never drains to 0 in steady state (T4); vmcnt(0) only at kt >= KT-2.
// Clobber-safety: B[buf] slots rewritten at ph2/ph3 are register-read at ph0,
// separated by >= 2 barriers from any wave's ph2 issue.

#define STAGE1(dstp, gp)                                                             \
    {                                                                                \
        u16* _d = (dstp);                                                            \
        const u16* _g = (gp);                                                        \
        __builtin_amdgcn_global_load_lds(GLOBAL_AS(_g + soff), LDS_AS(_d + doff),    \
                                         16, 0, 0);                                  \
        __builtin_amdgcn_global_load_lds(GLOBAL_AS(_g + 4096 + soff),                \
                                         LDS_AS(_d + 4096 + doff), 16, 0, 0);        \
    }

#define LDF(base, row, c0) \
    (*(const bf16x8*)&(base)[(row) * 64 + ((((c0) ^ ((row) & 7))) << 3)])

#define MFMA1(d, a, b) d = __builtin_amdgcn_mfma_f32_16x16x32_bf16(a, b, d, 0, 0, 0)

#define MFMA_BLOCK(R0, R1)                                                           \
    MFMA1(acc[R0][0], a00, b00); MFMA1(acc[R0][0], a01, b01);                        \
    MFMA1(acc[R0][1], a00, b10); MFMA1(acc[R0][1], a01, b11);                        \
    MFMA1(acc[R0][2], a00, b20); MFMA1(acc[R0][2], a01, b21);                        \
    MFMA1(acc[R0][3], a00, b30); MFMA1(acc[R0][3], a01, b31);                        \
    MFMA1(acc[R1][0], a10, b00); MFMA1(acc[R1][0], a11, b01);                        \
    MFMA1(acc[R1][1], a10, b10); MFMA1(acc[R1][1], a11, b11);                        \
    MFMA1(acc[R1][2], a10, b20); MFMA1(acc[R1][2], a11, b21);                        \
    MFMA1(acc[R1][3], a10, b30); MFMA1(acc[R1][3], a11, b31)

template <int KT>
__device__ __forceinline__ void gemm_core(const u16* tA0, const u16* tA1,
                                          const u16* tB0, const u16* tB1,
                                          u16* sm, floatx4 (&acc)[8][4], int tid) {
    const int w = tid >> 6, l = tid & 63;
    const int q = l >> 4, li = l & 15;
    const int wm = w >> 2, wn = w & 3;
    const int nrb = (wn & 1) * 64;
    const int soff = tid * 8;    // per-thread global element offset (16B chunks)
    const int doff = w * 512;    // wave-uniform LDS element offset (HW adds lane*16B)

    // prologue (steady-state issue order): B[0], A[0], B[1]; vmcnt(4) leaves B[1] in flight
    STAGE1(sm + 2 * TILE, tB0); STAGE1(sm + 3 * TILE, tB1);
    STAGE1(sm + 0 * TILE, tA0); STAGE1(sm + 1 * TILE, tA1);
    STAGE1(sm + 6 * TILE, tB0 + TILE); STAGE1(sm + 7 * TILE, tB1 + TILE);
    asm volatile("s_waitcnt vmcnt(4)");
    __builtin_amdgcn_s_barrier();

    int cur = 0;
#pragma unroll 1
    for (int kt = 0; kt < KT; ++kt) {
        const u16* At = sm + (size_t)((cur << 2) + wm) * TILE;
        const u16* Bt = sm + (size_t)((cur << 2) + 2 + (wn >> 1)) * TILE;
        u16* nbuf = sm + (size_t)(((cur ^ 1) << 2)) * TILE;
        u16* cbuf = sm + (size_t)((cur << 2)) * TILE;

        bf16x8 b00, b01, b10, b11, b20, b21, b30, b31;

        // ---------------- phase 0 : acc rows 0,1 ; stage A0[kt+1] ----------------
        {
            b00 = LDF(Bt, nrb + 0 * 16 + li, q);  b01 = LDF(Bt, nrb + 0 * 16 + li, 4 + q);
            b10 = LDF(Bt, nrb + 1 * 16 + li, q);  b11 = LDF(Bt, nrb + 1 * 16 + li, 4 + q);
            b20 = LDF(Bt, nrb + 2 * 16 + li, q);  b21 = LDF(Bt, nrb + 2 * 16 + li, 4 + q);
            b30 = LDF(Bt, nrb + 3 * 16 + li, q);  b31 = LDF(Bt, nrb + 3 * 16 + li, 4 + q);
            bf16x8 a00 = LDF(At, 0 * 16 + li, q), a01 = LDF(At, 0 * 16 + li, 4 + q);
            bf16x8 a10 = LDF(At, 1 * 16 + li, q), a11 = LDF(At, 1 * 16 + li, 4 + q);
            if (kt + 1 < KT) STAGE1(nbuf + 0 * TILE, tA0 + (size_t)(kt + 1) * TILE);
            __builtin_amdgcn_s_barrier();
            asm volatile("s_waitcnt lgkmcnt(0)");
            __builtin_amdgcn_s_setprio(1);
            MFMA_BLOCK(0, 1);
            __builtin_amdgcn_s_setprio(0);
            __builtin_amdgcn_s_barrier();
        }
        // ---------------- phase 1 : acc rows 2,3 ; stage A1[kt+1] ----------------
        {
            bf16x8 a00 = LDF(At, 2 * 16 + li, q), a01 = LDF(At, 2 * 16 + li, 4 + q);
            bf16x8 a10 = LDF(At, 3 * 16 + li, q), a11 = LDF(At, 3 * 16 + li, 4 + q);
            if (kt + 1 < KT) STAGE1(nbuf + 1 * TILE, tA1 + (size_t)(kt + 1) * TILE);
            __builtin_amdgcn_s_barrier();
            asm volatile("s_waitcnt lgkmcnt(0)");
            __builtin_amdgcn_s_setprio(1);
            MFMA_BLOCK(2, 3);
            __builtin_amdgcn_s_setprio(0);
            __builtin_amdgcn_s_barrier();
        }
        // ---------------- phase 2 : acc rows 4,5 ; stage B0[kt+2] ----------------
        {
            bf16x8 a00 = LDF(At, 4 * 16 + li, q), a01 = LDF(At, 4 * 16 + li, 4 + q);
            bf16x8 a10 = LDF(At, 5 * 16 + li, q), a11 = LDF(At, 5 * 16 + li, 4 + q);
            if (kt + 2 < KT) STAGE1(cbuf + 2 * TILE, tB0 + (size_t)(kt + 2) * TILE);
            __builtin_amdgcn_s_barrier();
            asm volatile("s_waitcnt lgkmcnt(0)");
            __builtin_amdgcn_s_setprio(1);
            MFMA_BLOCK(4, 5);
            __builtin_amdgcn_s_setprio(0);
            __builtin_amdgcn_s_barrier();
        }
        // ---------------- phase 3 : acc rows 6,7 ; stage B1[kt+2] ; counted wait --
        {
            bf16x8 a00 = LDF(At, 6 * 16 + li, q), a01 = LDF(At, 6 * 16 + li, 4 + q);
            bf16x8 a10 = LDF(At, 7 * 16 + li, q), a11 = LDF(At, 7 * 16 + li, 4 + q);
            if (kt + 2 < KT) STAGE1(cbuf + 3 * TILE, tB1 + (size_t)(kt + 2) * TILE);
            if (kt < KT - 2) { asm volatile("s_waitcnt vmcnt(4)"); }
            else             { asm volatile("s_waitcnt vmcnt(0)"); }
            __builtin_amdgcn_s_barrier();
            asm volatile("s_waitcnt lgkmcnt(0)");
            __builtin_amdgcn_s_setprio(1);
            MFMA_BLOCK(6, 7);
            __builtin_amdgcn_s_setprio(0);
            __builtin_amdgcn_s_barrier();
        }
        cur ^= 1;
    }
}

// ---------------- pass A: h = relu(x @ W1 + b1), bf16 tiled out ----------------
// grid = 8 experts x 8 n256-tiles x 4 m256-tiles = 256; e = bx&7 keeps each
// expert's A/B panels resident in one XCD's L2.
__global__ __launch_bounds__(512) void gemm_a(
        const u16* __restrict__ At, const u16* __restrict__ Bt,
        const float* __restrict__ bias, u16* __restrict__ hsT,
        const int* __restrict__ cnt, const int* __restrict__ offs) {
    __shared__ u16 sm[2 * 4 * TILE];   // 128 KiB
    int bx = blockIdx.x;
    int e = bx & 7;
    int r = bx >> 3;
    int nt = r & 7;
    int mt0 = r >> 3;
    int count = cnt[e];
    int base128 = offs[e] >> 7;
    int tid = threadIdx.x;
    int w = tid >> 6, l = tid & 63, q = l >> 4, li = l & 15;
    int wm = w >> 2, wn = w & 3;
#pragma unroll 1
    for (int mt = mt0; mt * 256 < count; mt += 4) {
        const u16* a0 = At + (size_t)((base128 + mt * 2 + 0) * 8) * TILE;
        const u16* a1 = At + (size_t)((base128 + mt * 2 + 1) * 8) * TILE;
        const u16* b0 = Bt + (size_t)((e * 16 + nt * 2 + 0) * 8) * TILE;
        const u16* b1 = Bt + (size_t)((e * 16 + nt * 2 + 1) * 8) * TILE;
        floatx4 acc[8][4];
#pragma unroll
        for (int a = 0; a < 8; ++a)
#pragma unroll
            for (int b = 0; b < 4; ++b) acc[a][b] = (floatx4)0.0f;
        gemm_core<8>(a0, a1, b0, b1, sm, acc, tid);

        // epilogue: each wave owns exactly one 128x64 hsT tile
        // (rows = wm-half of 256-block, cols = wn 64-group); build swizzled image
        // in its private 16KB LDS region, then dump fully-contiguous.
        float bv[4];
#pragma unroll
        for (int fn = 0; fn < 4; ++fn)
            bv[fn] = bias[(size_t)e * DH + nt * 256 + wn * 64 + fn * 16 + li];
        u16* img = sm + (size_t)w * TILE;
#pragma unroll
        for (int fm = 0; fm < 8; ++fm)
#pragma unroll
            for (int fn = 0; fn < 4; ++fn)
#pragma unroll
                for (int rr = 0; rr < 4; ++rr) {
                    float v = acc[fm][fn][rr] + bv[fn];
                    v = v > 0.0f ? v : 0.0f;
                    img[slot_off(fm * 16 + q * 4 + rr, fn * 16 + li)] = f2bf(v);
                }
        __syncthreads();
        int t128 = mt * 2 + wm;
        if (t128 * 128 < count) {   // guard: don't write past this expert's segment
            u16* dst = hsT + ((size_t)(base128 + t128) * 32 + nt * 4 + wn) * TILE;
#pragma unroll
            for (int j = 0; j < 16; ++j)
                *(ushort8*)&dst[j * 512 + l * 8] = *(const ushort8*)&img[j * 512 + l * 8];
        }
        __syncthreads();   // LDS safe for next m-tile's prologue
    }
}

// ---------------- pass B: partial[ks] = h @ W2 over K-half, fp32 sorted layout ----------
// grid = 8 experts x 2 n256-tiles x 2 k-splits x 4 m256-tiles = 128
__global__ __launch_bounds__(512) void gemm_b(
        const u16* __restrict__ At, const u16* __restrict__ Bt,
        float* __restrict__ ps, const int* __restrict__ cnt,
        const int* __restrict__ offs) {
    __shared__ u16 sm[2 * 4 * TILE];   // 128 KiB
    int bx = blockIdx.x;
    int e = bx & 7;
    int r = bx >> 3;
    int nt = r & 1;
    int ks = (r >> 1) & 1;
    int mt0 = r >> 2;
    int count = cnt[e];
    int seg = offs[e];
    int base128 = seg >> 7;
    int tid = threadIdx.x;
    int w = tid >> 6, l = tid & 63, q = l >> 4, li = l & 15;
    int wm = w >> 2, wn = w & 3;
#pragma unroll 1
    for (int mt = mt0; mt * 256 < count; mt += 4) {
        const u16* a0 = At + (size_t)((base128 + mt * 2 + 0) * 32 + ks * 16) * TILE;
        const u16* a1 = At + (size_t)((base128 + mt * 2 + 1) * 32 + ks * 16) * TILE;
        const u16* b0 = Bt + (size_t)((e * 4 + nt * 2 + 0) * 32 + ks * 16) * TILE;
        const u16* b1 = Bt + (size_t)((e * 4 + nt * 2 + 1) * 32 + ks * 16) * TILE;
        floatx4 acc[8][4];
#pragma unroll
        for (int a = 0; a < 8; ++a)
#pragma unroll
            for (int b = 0; b < 4; ++b) acc[a][b] = (floatx4)0.0f;
        gemm_core<16>(a0, a1, b0, b1, sm, acc, tid);

        // direct fp32 stores; guard second m128-half against segment overflow
        int t128 = mt * 2 + wm;
        if (t128 * 128 < count) {
            float* pbase = ps + ((size_t)ks * ROWCAP + seg + (size_t)mt * 256) * DOUT;
#pragma unroll
            for (int fn = 0; fn < 4; ++fn) {
                int col = nt * 256 + wn * 64 + fn * 16 + li;
#pragma unroll
                for (int fm = 0; fm < 8; ++fm) {
                    int row0 = wm * 128 + fm * 16 + q * 4;
#pragma unroll
                    for (int rr = 0; rr < 4; ++rr)
                        pbase[(size_t)(row0 + rr) * DOUT + col] = acc[fm][fn][rr];
                }
            }
        }
        // no barrier needed: next prologue only touches LDS; all waves already
        // passed the core's final phase barrier (global stores don't alias LDS)
    }
}

// ---------------- reduce: out[i] = ps[0][rpos[i]] + ps[1][rpos[i]] + b2[groups[i]] ------
__global__ __launch_bounds__(256) void reduce_b(
        const float* __restrict__ ps, const int* __restrict__ rpos,
        const int* __restrict__ groups, const float* __restrict__ b2,
        float* __restrict__ out) {
    int idx = blockIdx.x * 256 + threadIdx.x;
    int i = idx >> 7;
    int c = (idx & 127) * 4;
    int pos = rpos[i];
    int g = groups[i];
    const float4 v0 = *(const float4*)&ps[(size_t)pos * DOUT + c];
    const float4 v1 = *(const float4*)&ps[((size_t)ROWCAP + pos) * DOUT + c];
    const float4 bb = *(const float4*)&b2[(size_t)g * DOUT + c];
    float4 o;
    o.x = v0.x + v1.x + bb.x; o.y = v0.y + v1.y + bb.y;
    o.z = v0.z + v1.z + bb.z; o.w = v0.w + v1.w + bb.w;
    *(float4*)&out[(size_t)i * DOUT + c] = o;
}

// ---------------- launch ----------------
extern "C" void kernel_launch(void* const* d_in, const int* in_sizes, int n_in,
                              void* d_out, int out_size, void* d_ws, size_t ws_size,
                              hipStream_t stream) {
    const float* x = (const float*)d_in[0];
    const int* groups = (const int*)d_in[1];
    const float* W1 = (const float*)d_in[2];
    const float* b1 = (const float*)d_in[3];
    const float* W2 = (const float*)d_in[4];
    const float* b2 = (const float*)d_in[5];
    float* out = (float*)d_out;

    char* ws = (char*)d_ws;
    size_t o = 0;
    auto alloc = [&](size_t bytes) {
        void* p = ws + o;
        o = (o + bytes + 255) & ~(size_t)255;
        return p;
    };
    int* cnt = (int*)alloc(NEXP * 4);
    int* offs = (int*)alloc(NEXP * 4);
    int* perm = (int*)alloc((size_t)ROWCAP * 4);
    int* rpos = (int*)alloc((size_t)NB * 4);
    u16* xsT = (u16*)alloc((size_t)(ROWCAP / 128) * 8 * TILE * 2);    // ~9.4 MB
    u16* w1tT = (u16*)alloc((size_t)NEXP * DIN * DH * 2);             // 16.8 MB
    u16* w2tT = (u16*)alloc((size_t)NEXP * DH * DOUT * 2);            // 16.8 MB
    u16* hsT = (u16*)alloc((size_t)(ROWCAP / 128) * 32 * TILE * 2);   // ~37.7 MB
    float* ps = (float*)alloc((size_t)2 * ROWCAP * DOUT * 4);         // ~37.7 MB

    route_kernel<<<1, 256, 0, stream>>>(groups, cnt, offs, perm, rpos);
    prep_kernel<<<6144, 256, 0, stream>>>(x, W1, W2, rpos, xsT, w1tT, w2tT);
    gemm_a<<<256, 512, 0, stream>>>(xsT, w1tT, b1, hsT, cnt, offs);
    gemm_b<<<128, 512, 0, stream>>>(hsT, w2tT, ps, cnt, offs);
    reduce_b<<<(NB * (DOUT / 4)) / 256, 256, 0, stream>>>(ps, rpos, groups, b2, out);
}

// Round 5
// 282.053 us; speedup vs baseline: 1.3670x; 1.3638x over previous
//
#include <hip/hip_runtime.h>
#include <hip/hip_bf16.h>

typedef unsigned short u16;
typedef __bf16 bf16x8 __attribute__((ext_vector_type(8)));
typedef float floatx4 __attribute__((ext_vector_type(4)));
typedef unsigned short ushort8 __attribute__((ext_vector_type(8)));

#define GLOBAL_AS(p) ((const __attribute__((address_space(1))) void*)(p))
#define LDS_AS(p) ((__attribute__((address_space(3))) void*)(p))

constexpr int NB = 8192;
constexpr int DIN = 512;
constexpr int DH = 2048;
constexpr int DOUT = 512;
constexpr int NEXP = 8;
constexpr int ROWCAP = NB + NEXP * 128;    // 128-padded segments (write-side bound)
constexpr int RCAPRD = NB + NEXP * 256;    // read-side row capacity (256-tile overread pad)
constexpr int TILE = 8192;                 // elements in a 128x64 bf16 tile

__device__ __forceinline__ u16 f2bf(float f) {
    unsigned u = __builtin_bit_cast(unsigned, f);
    unsigned r = u + 0x7FFFu + ((u >> 16) & 1u);
    return (u16)(r >> 16);
}

// element offset within a 128x64 tile for (row, klocal), xor-swizzled 16B chunks
__device__ __forceinline__ int slot_off(int row, int kl) {
    return row * 64 + ((((kl >> 3) ^ (row & 7)) << 3) | (kl & 7));
}

// ---------------- routing: one single-block kernel, per-wave sub-counters ----------------
__global__ void route_kernel(const int* __restrict__ groups, int* __restrict__ cnt,
                             int* __restrict__ offs, int* __restrict__ perm,
                             int* __restrict__ rpos) {
    __shared__ int wc[NEXP * 4];    // [e][wave] counts
    __shared__ int lcur[NEXP * 4];  // running positions
    int t = threadIdx.x;
    int w = t >> 6;
    if (t < NEXP * 4) wc[t] = 0;
    __syncthreads();
    for (int i = t; i < NB; i += 256) atomicAdd(&wc[groups[i] * 4 + w], 1);
    __syncthreads();
    if (t == 0) {
        int run = 0;
        for (int e = 0; e < NEXP; ++e) {
            offs[e] = run;
            int s = run;
            for (int j = 0; j < 4; ++j) { lcur[e * 4 + j] = s; s += wc[e * 4 + j]; }
            cnt[e] = s - run;
            run += (((s - run) + 127) >> 7) << 7;   // 128-aligned segments
        }
    }
    __syncthreads();
    for (int i = t; i < NB; i += 256) {
        int e = groups[i];
        int pos = atomicAdd(&lcur[e * 4 + w], 1);
        perm[pos] = i;
        rpos[i] = pos;
    }
}

// ---------------- fused wide prep: W1/W2 transpose+tile | gather-x ----------------
// grid.x = 4096 (weights) + 2048 (gather) = 6144
__global__ __launch_bounds__(256) void prep_kernel(
        const float* __restrict__ x, const float* __restrict__ W1,
        const float* __restrict__ W2, const int* __restrict__ rpos,
        u16* __restrict__ xsT, u16* __restrict__ w1tT, u16* __restrict__ w2tT) {
    int bx = blockIdx.x;
    int t = threadIdx.x;
    if (bx < 4096) {
        // weight transpose+convert+tile: src [E][K][N] -> tiled [e][nt][kt][128][64]
        __shared__ float tile[64][65];
        bool isW1 = bx < 2048;
        int b = isW1 ? bx : bx - 2048;
        int e = b >> 8;
        int q = b & 255;
        int C = isW1 ? DH : DOUT;                 // N-dim
        int NTP = C >> 7;                         // n-tiles (16 / 4)
        int KTP = isW1 ? (DIN >> 6) : (DH >> 6);  // k-tiles (8 / 32)
        int rt = isW1 ? (q >> 5) : (q >> 3);      // k 64-tile idx
        int ct = isW1 ? (q & 31) : (q & 7);       // n 64-tile idx
        const float* s = (isW1 ? W1 : W2) + (size_t)e * (isW1 ? DIN * DH : DH * DOUT);
        u16* d = isW1 ? w1tT : w2tT;
        int r0 = rt * 64, c0 = ct * 64;
        for (int i = 0; i < 4; ++i) {
            int r = (t >> 4) + i * 16;
            int c = (t & 15) * 4;
            const float4 v = *(const float4*)&s[(size_t)(r0 + r) * C + c0 + c];
            tile[r][c] = v.x; tile[r][c + 1] = v.y; tile[r][c + 2] = v.z; tile[r][c + 3] = v.w;
        }
        __syncthreads();
        for (int i = 0; i < 4; ++i) {
            int c = (t >> 4) + i * 16;    // n-local
            int r = (t & 15) * 4;         // k-local, 4 consecutive
            int n = c0 + c, k = r0 + r;
            ushort4 o;
            o.x = f2bf(tile[r][c]); o.y = f2bf(tile[r + 1][c]);
            o.z = f2bf(tile[r + 2][c]); o.w = f2bf(tile[r + 3][c]);
            size_t off = ((size_t)(e * NTP + (n >> 7)) * KTP + (k >> 6)) * TILE
                         + slot_off(n & 127, k & 63);
            *(ushort4*)&d[off] = o;
        }
    } else {
        // gather-x: 4 rows per block, 64 lanes per row, 8 elems/lane
        int r = t >> 6, lane = t & 63;
        int i = (bx - 4096) * 4 + r;
        int pos = rpos[i];
        int k = lane * 8;
        const float4 a = *(const float4*)&x[(size_t)i * DIN + k];
        const float4 b = *(const float4*)&x[(size_t)i * DIN + k + 4];
        ushort8 o;
        o[0] = f2bf(a.x); o[1] = f2bf(a.y); o[2] = f2bf(a.z); o[3] = f2bf(a.w);
        o[4] = f2bf(b.x); o[5] = f2bf(b.y); o[6] = f2bf(b.z); o[7] = f2bf(b.w);
        int lp = pos & 127;
        size_t off = (size_t)(pos >> 7) * 8 * TILE + (size_t)(k >> 6) * TILE
                     + slot_off(lp, k & 63);
        *(ushort8*)&xsT[off] = o;
    }
}

// ---------------- 256x256-tile GEMM building blocks, 1024-thread / 16-wave ----------------
// Per K-step LDS image: 4 slots {A0 (rows 0-127), A1 (rows 128-255), B0, B1},
// each a 128x64 pre-swizzled tile (16 KB). Double-buffered: 8 slots = 128 KiB.
// Wave (wm,wn), wm=w>>2, wn=w&3, owns output rows [wm*64,+64) x cols [wn*64,+64):
// acc[4][4] = 64 VGPRs/lane -> total ~115 VGPR, fits the hard 128 cap for
// 1024-thread blocks (rounds 2-4: 512-thread/acc[8][4] designs spill under the
// cap regardless of launch_bounds -> design must fit 128).

#define LDF(base, row, c0) \
    (*(const bf16x8*)&(base)[(row) * 64 + ((((c0) ^ ((row) & 7))) << 3)])

// one global_load_lds per thread per slot: 1024 threads x 16B = 16 KB tile
__device__ __forceinline__ void stage4(const u16* a0, const u16* a1,
                                       const u16* b0, const u16* b1,
                                       u16* buf, int soff, int doff) {
    __builtin_amdgcn_global_load_lds(GLOBAL_AS(a0 + soff), LDS_AS(buf + 0 * TILE + doff), 16, 0, 0);
    __builtin_amdgcn_global_load_lds(GLOBAL_AS(a1 + soff), LDS_AS(buf + 1 * TILE + doff), 16, 0, 0);
    __builtin_amdgcn_global_load_lds(GLOBAL_AS(b0 + soff), LDS_AS(buf + 2 * TILE + doff), 16, 0, 0);
    __builtin_amdgcn_global_load_lds(GLOBAL_AS(b1 + soff), LDS_AS(buf + 3 * TILE + doff), 16, 0, 0);
}

__device__ __forceinline__ void compute_step(const u16* At, const u16* Bt,
                                             int arow, int brow,
                                             floatx4 (&acc)[4][4], int q, int li) {
#pragma unroll
    for (int s = 0; s < 2; ++s) {
        int c0 = s * 4 + q;
        bf16x8 bfr[4];
#pragma unroll
        for (int fn = 0; fn < 4; ++fn) bfr[fn] = LDF(Bt, brow + fn * 16 + li, c0);
#pragma unroll
        for (int fm = 0; fm < 4; ++fm) {
            bf16x8 af = LDF(At, arow + fm * 16 + li, c0);
#pragma unroll
            for (int fn = 0; fn < 4; ++fn)
                acc[fm][fn] = __builtin_amdgcn_mfma_f32_16x16x32_bf16(
                    af, bfr[fn], acc[fm][fn], 0, 0, 0);
        }
    }
}

// ---------------- pass A: h = relu(x @ W1 + b1), bf16 tiled out ----------------
// grid = 8 experts x 8 n256-tiles x 5 m256-slots = 320; e = bx&7 (XCD affinity)
__global__ __launch_bounds__(1024) void gemm_a(
        const u16* __restrict__ At, const u16* __restrict__ Bt,
        const float* __restrict__ bias, u16* __restrict__ hsT,
        const int* __restrict__ cnt, const int* __restrict__ offs) {
    __shared__ u16 sm[2 * 4 * TILE];   // 128 KiB
    int bx = blockIdx.x;
    int e = bx & 7;
    int r = bx >> 3;
    int nt = r & 7;
    int mt0 = r >> 3;
    int count = cnt[e];
    int base128 = offs[e] >> 7;
    int tid = threadIdx.x;
    int w = tid >> 6, l = tid & 63, q = l >> 4, li = l & 15;
    int wm = w >> 2, wn = w & 3;
    int arow = (wm & 1) * 64, brow = (wn & 1) * 64;
    int soff = tid * 8, doff = w * 512;
#pragma unroll 1
    for (int mt = mt0; mt * 256 < count; mt += 5) {
        const u16* a0 = At + (size_t)((base128 + mt * 2 + 0) * 8) * TILE;
        const u16* a1 = At + (size_t)((base128 + mt * 2 + 1) * 8) * TILE;
        const u16* b0 = Bt + (size_t)((e * 16 + nt * 2 + 0) * 8) * TILE;
        const u16* b1 = Bt + (size_t)((e * 16 + nt * 2 + 1) * 8) * TILE;
        floatx4 acc[4][4];
#pragma unroll
        for (int a = 0; a < 4; ++a)
#pragma unroll
            for (int b = 0; b < 4; ++b) acc[a][b] = (floatx4)0.0f;

        // 2-phase pipeline: stage next K-tile, compute current, one sync per step
        stage4(a0, a1, b0, b1, sm, soff, doff);
        __syncthreads();
        int cur = 0;
#pragma unroll 1
        for (int kt = 0; kt < 8; ++kt) {
            if (kt + 1 < 8)
                stage4(a0 + (kt + 1) * TILE, a1 + (kt + 1) * TILE,
                       b0 + (kt + 1) * TILE, b1 + (kt + 1) * TILE,
                       sm + (cur ^ 1) * 4 * TILE, soff, doff);
            const u16* Atile = sm + (size_t)(cur * 4 + (wm >> 1)) * TILE;
            const u16* Btile = sm + (size_t)(cur * 4 + 2 + (wn >> 1)) * TILE;
            compute_step(Atile, Btile, arow, brow, acc, q, li);
            __syncthreads();   // drains prefetch (vmcnt) AFTER compute: latency hidden
            cur ^= 1;
        }

        // epilogue: wave owns 64x64; build swizzled image in its private 8 KB LDS
        // region, dump fully-contiguous (lane-16B reads: conflict-free)
        float bv[4];
#pragma unroll
        for (int fn = 0; fn < 4; ++fn)
            bv[fn] = bias[(size_t)e * DH + nt * 256 + wn * 64 + fn * 16 + li];
        u16* img = sm + (size_t)w * 4096;
#pragma unroll
        for (int fm = 0; fm < 4; ++fm)
#pragma unroll
            for (int fn = 0; fn < 4; ++fn)
#pragma unroll
                for (int rr = 0; rr < 4; ++rr) {
                    float v = acc[fm][fn][rr] + bv[fn];
                    v = v > 0.0f ? v : 0.0f;
                    int row = fm * 16 + q * 4 + rr;   // 0..63 (local)
                    int col = fn * 16 + li;           // 0..63 (k-local in hsT tile)
                    img[row * 64 + ((((col >> 3) ^ (row & 7)) << 3) | (col & 7))] = f2bf(v);
                }
        // own-region write->read: HW lgkmcnt ordering suffices, no block sync
        if ((mt * 2 + (wm >> 1)) * 128 < count) {
            u16* dst = hsT + ((size_t)(base128 + mt * 2 + (wm >> 1)) * 32 + nt * 4 + wn) * TILE
                       + (wm & 1) * 4096;
#pragma unroll
            for (int j = 0; j < 8; ++j)
                *(ushort8*)&dst[j * 512 + l * 8] = *(const ushort8*)&img[j * 512 + l * 8];
        }
        __syncthreads();   // img regions reused as staging buffers next m-iter
    }
}

// ---------------- pass B: partial[ks] = h @ W2 over K-half, fp32 sorted layout ----------
// grid = 8 experts x 2 n256-tiles x 2 k-splits x 5 m256-slots = 160
__global__ __launch_bounds__(1024) void gemm_b(
        const u16* __restrict__ At, const u16* __restrict__ Bt,
        float* __restrict__ ps, const int* __restrict__ cnt,
        const int* __restrict__ offs) {
    __shared__ u16 sm[2 * 4 * TILE];   // 128 KiB
    int bx = blockIdx.x;
    int e = bx & 7;
    int r = bx >> 3;
    int nt = r & 1;
    int ks = (r >> 1) & 1;
    int mt0 = r >> 2;
    int count = cnt[e];
    int seg = offs[e];
    int base128 = seg >> 7;
    int tid = threadIdx.x;
    int w = tid >> 6, l = tid & 63, q = l >> 4, li = l & 15;
    int wm = w >> 2, wn = w & 3;
    int arow = (wm & 1) * 64, brow = (wn & 1) * 64;
    int soff = tid * 8, doff = w * 512;
#pragma unroll 1
    for (int mt = mt0; mt * 256 < count; mt += 5) {
        const u16* a0 = At + (size_t)((base128 + mt * 2 + 0) * 32 + ks * 16) * TILE;
        const u16* a1 = At + (size_t)((base128 + mt * 2 + 1) * 32 + ks * 16) * TILE;
        const u16* b0 = Bt + (size_t)((e * 4 + nt * 2 + 0) * 32 + ks * 16) * TILE;
        const u16* b1 = Bt + (size_t)((e * 4 + nt * 2 + 1) * 32 + ks * 16) * TILE;
        floatx4 acc[4][4];
#pragma unroll
        for (int a = 0; a < 4; ++a)
#pragma unroll
            for (int b = 0; b < 4; ++b) acc[a][b] = (floatx4)0.0f;

        stage4(a0, a1, b0, b1, sm, soff, doff);
        __syncthreads();
        int cur = 0;
#pragma unroll 1
        for (int kt = 0; kt < 16; ++kt) {
            if (kt + 1 < 16)
                stage4(a0 + (kt + 1) * TILE, a1 + (kt + 1) * TILE,
                       b0 + (kt + 1) * TILE, b1 + (kt + 1) * TILE,
                       sm + (cur ^ 1) * 4 * TILE, soff, doff);
            const u16* Atile = sm + (size_t)(cur * 4 + (wm >> 1)) * TILE;
            const u16* Btile = sm + (size_t)(cur * 4 + 2 + (wn >> 1)) * TILE;
            compute_step(Atile, Btile, arow, brow, acc, q, li);
            __syncthreads();
            cur ^= 1;
        }

        // direct fp32 stores; guard per 128-row half against segment overflow
        if ((mt * 2 + (wm >> 1)) * 128 < count) {
            float* pbase = ps + ((size_t)ks * ROWCAP + seg + (size_t)mt * 256) * DOUT;
#pragma unroll
            for (int fn = 0; fn < 4; ++fn) {
                int col = nt * 256 + wn * 64 + fn * 16 + li;
#pragma unroll
                for (int fm = 0; fm < 4; ++fm) {
                    int row0 = wm * 64 + fm * 16 + q * 4;
#pragma unroll
                    for (int rr = 0; rr < 4; ++rr)
                        pbase[(size_t)(row0 + rr) * DOUT + col] = acc[fm][fn][rr];
                }
            }
        }
        __syncthreads();   // LDS reuse across m-iterations
    }
}

// ---------------- reduce: out[i] = ps[0][rpos[i]] + ps[1][rpos[i]] + b2[groups[i]] ------
__global__ __launch_bounds__(256) void reduce_b(
        const float* __restrict__ ps, const int* __restrict__ rpos,
        const int* __restrict__ groups, const float* __restrict__ b2,
        float* __restrict__ out) {
    int idx = blockIdx.x * 256 + threadIdx.x;
    int i = idx >> 7;
    int c = (idx & 127) * 4;
    int pos = rpos[i];
    int g = groups[i];
    const float4 v0 = *(const float4*)&ps[(size_t)pos * DOUT + c];
    const float4 v1 = *(const float4*)&ps[((size_t)ROWCAP + pos) * DOUT + c];
    const float4 bb = *(const float4*)&b2[(size_t)g * DOUT + c];
    float4 o;
    o.x = v0.x + v1.x + bb.x; o.y = v0.y + v1.y + bb.y;
    o.z = v0.z + v1.z + bb.z; o.w = v0.w + v1.w + bb.w;
    *(float4*)&out[(size_t)i * DOUT + c] = o;
}

// ---------------- launch ----------------
extern "C" void kernel_launch(void* const* d_in, const int* in_sizes, int n_in,
                              void* d_out, int out_size, void* d_ws, size_t ws_size,
                              hipStream_t stream) {
    const float* x = (const float*)d_in[0];
    const int* groups = (const int*)d_in[1];
    const float* W1 = (const float*)d_in[2];
    const float* b1 = (const float*)d_in[3];
    const float* W2 = (const float*)d_in[4];
    const float* b2 = (const float*)d_in[5];
    float* out = (float*)d_out;

    char* ws = (char*)d_ws;
    size_t o = 0;
    auto alloc = [&](size_t bytes) {
        void* p = ws + o;
        o = (o + bytes + 255) & ~(size_t)255;
        return p;
    };
    int* cnt = (int*)alloc(NEXP * 4);
    int* offs = (int*)alloc(NEXP * 4);
    int* perm = (int*)alloc((size_t)ROWCAP * 4);
    int* rpos = (int*)alloc((size_t)NB * 4);
    u16* xsT = (u16*)alloc((size_t)(RCAPRD / 128) * 8 * TILE * 2);    // ~10.5 MB (read-pad)
    u16* w1tT = (u16*)alloc((size_t)NEXP * DIN * DH * 2);             // 16.8 MB
    u16* w2tT = (u16*)alloc((size_t)NEXP * DH * DOUT * 2);            // 16.8 MB
    u16* hsT = (u16*)alloc((size_t)(RCAPRD / 128) * 32 * TILE * 2);   // ~41.9 MB (read-pad)
    float* ps = (float*)alloc((size_t)2 * ROWCAP * DOUT * 4);         // ~37.7 MB

    route_kernel<<<1, 256, 0, stream>>>(groups, cnt, offs, perm, rpos);
    prep_kernel<<<6144, 256, 0, stream>>>(x, W1, W2, rpos, xsT, w1tT, w2tT);
    gemm_a<<<NEXP * 8 * 5, 1024, 0, stream>>>(xsT, w1tT, b1, hsT, cnt, offs);
    gemm_b<<<NEXP * 2 * 2 * 5, 1024, 0, stream>>>(hsT, w2tT, ps, cnt, offs);
    reduce_b<<<(NB * (DOUT / 4)) / 256, 256, 0, stream>>>(ps, rpos, groups, b2, out);
}

// Round 6
// 228.204 us; speedup vs baseline: 1.6895x; 1.2360x over previous
//
#include <hip/hip_runtime.h>
#include <hip/hip_bf16.h>

typedef unsigned short u16;
typedef __bf16 bf16x8 __attribute__((ext_vector_type(8)));
typedef float floatx4 __attribute__((ext_vector_type(4)));
typedef unsigned short ushort8 __attribute__((ext_vector_type(8)));

#define GLOBAL_AS(p) ((const __attribute__((address_space(1))) void*)(p))
#define LDS_AS(p) ((__attribute__((address_space(3))) void*)(p))

constexpr int NB = 8192;
constexpr int DIN = 512;
constexpr int DH = 2048;
constexpr int DOUT = 512;
constexpr int NEXP = 8;
constexpr int ROWCAP = NB + NEXP * 128;    // 128-padded segments (write-side bound)
constexpr int RCAPRD = NB + NEXP * 256;    // read-side row capacity (256-tile overread pad)
constexpr int TILE = 8192;                 // elements in a 128x64 bf16 tile

__device__ __forceinline__ u16 f2bf(float f) {
    unsigned u = __builtin_bit_cast(unsigned, f);
    unsigned r = u + 0x7FFFu + ((u >> 16) & 1u);
    return (u16)(r >> 16);
}

// element offset within a 128x64 tile for (row, klocal), xor-swizzled 16B chunks
__device__ __forceinline__ int slot_off(int row, int kl) {
    return row * 64 + ((((kl >> 3) ^ (row & 7)) << 3) | (kl & 7));
}

// ---------------- routing: one single-block kernel, per-wave sub-counters ----------------
__global__ void route_kernel(const int* __restrict__ groups, int* __restrict__ cnt,
                             int* __restrict__ offs, int* __restrict__ perm,
                             int* __restrict__ rpos) {
    __shared__ int wc[NEXP * 4];    // [e][wave] counts
    __shared__ int lcur[NEXP * 4];  // running positions
    int t = threadIdx.x;
    int w = t >> 6;
    if (t < NEXP * 4) wc[t] = 0;
    __syncthreads();
    for (int i = t; i < NB; i += 256) atomicAdd(&wc[groups[i] * 4 + w], 1);
    __syncthreads();
    if (t == 0) {
        int run = 0;
        for (int e = 0; e < NEXP; ++e) {
            offs[e] = run;
            int s = run;
            for (int j = 0; j < 4; ++j) { lcur[e * 4 + j] = s; s += wc[e * 4 + j]; }
            cnt[e] = s - run;
            run += (((s - run) + 127) >> 7) << 7;   // 128-aligned segments
        }
    }
    __syncthreads();
    for (int i = t; i < NB; i += 256) {
        int e = groups[i];
        int pos = atomicAdd(&lcur[e * 4 + w], 1);
        perm[pos] = i;
        rpos[i] = pos;
    }
}

// ---------------- fused wide prep: W1/W2 transpose+tile | gather-x ----------------
// grid.x = 4096 (weights) + 2048 (gather) = 6144
__global__ __launch_bounds__(256) void prep_kernel(
        const float* __restrict__ x, const float* __restrict__ W1,
        const float* __restrict__ W2, const int* __restrict__ rpos,
        u16* __restrict__ xsT, u16* __restrict__ w1tT, u16* __restrict__ w2tT) {
    int bx = blockIdx.x;
    int t = threadIdx.x;
    if (bx < 4096) {
        // weight transpose+convert+tile: src [E][K][N] -> tiled [e][nt][kt][128][64]
        __shared__ float tile[64][65];
        bool isW1 = bx < 2048;
        int b = isW1 ? bx : bx - 2048;
        int e = b >> 8;
        int q = b & 255;
        int C = isW1 ? DH : DOUT;                 // N-dim
        int NTP = C >> 7;                         // n-tiles (16 / 4)
        int KTP = isW1 ? (DIN >> 6) : (DH >> 6);  // k-tiles (8 / 32)
        int rt = isW1 ? (q >> 5) : (q >> 3);      // k 64-tile idx
        int ct = isW1 ? (q & 31) : (q & 7);       // n 64-tile idx
        const float* s = (isW1 ? W1 : W2) + (size_t)e * (isW1 ? DIN * DH : DH * DOUT);
        u16* d = isW1 ? w1tT : w2tT;
        int r0 = rt * 64, c0 = ct * 64;
        for (int i = 0; i < 4; ++i) {
            int r = (t >> 4) + i * 16;
            int c = (t & 15) * 4;
            const float4 v = *(const float4*)&s[(size_t)(r0 + r) * C + c0 + c];
            tile[r][c] = v.x; tile[r][c + 1] = v.y; tile[r][c + 2] = v.z; tile[r][c + 3] = v.w;
        }
        __syncthreads();
        for (int i = 0; i < 4; ++i) {
            int c = (t >> 4) + i * 16;    // n-local
            int r = (t & 15) * 4;         // k-local, 4 consecutive
            int n = c0 + c, k = r0 + r;
            ushort4 o;
            o.x = f2bf(tile[r][c]); o.y = f2bf(tile[r + 1][c]);
            o.z = f2bf(tile[r + 2][c]); o.w = f2bf(tile[r + 3][c]);
            size_t off = ((size_t)(e * NTP + (n >> 7)) * KTP + (k >> 6)) * TILE
                         + slot_off(n & 127, k & 63);
            *(ushort4*)&d[off] = o;
        }
    } else {
        // gather-x: 4 rows per block, 64 lanes per row, 8 elems/lane
        int r = t >> 6, lane = t & 63;
        int i = (bx - 4096) * 4 + r;
        int pos = rpos[i];
        int k = lane * 8;
        const float4 a = *(const float4*)&x[(size_t)i * DIN + k];
        const float4 b = *(const float4*)&x[(size_t)i * DIN + k + 4];
        ushort8 o;
        o[0] = f2bf(a.x); o[1] = f2bf(a.y); o[2] = f2bf(a.z); o[3] = f2bf(a.w);
        o[4] = f2bf(b.x); o[5] = f2bf(b.y); o[6] = f2bf(b.z); o[7] = f2bf(b.w);
        int lp = pos & 127;
        size_t off = (size_t)(pos >> 7) * 8 * TILE + (size_t)(k >> 6) * TILE
                     + slot_off(lp, k & 63);
        *(ushort8*)&xsT[off] = o;
    }
}

// ---------------- 256x128-tile GEMM building blocks, 512-thread / 8-wave ----------------
// VGPR discipline (rounds 2-5 evidence): allocator budget = 131072/(2*threads)
// per thread: 512-thr -> 128. Per-wave acc[4][4] (64 VGPR) + frags (~20) +
// addressing fits. amdgpu_waves_per_eu(2) additionally requests the 256-cap
// (2 waves/EU); LDS (96KB) limits to 1 block/CU either way, so no occupancy
// cost if the attribute takes effect.
// Per K-step LDS image: 3 slots {A0 rows 0-127, A1 rows 128-255, B n 0-127},
// each a 128x64 pre-swizzled tile (16 KB). Double-buffered: 6 slots = 96 KiB.
// Waves: w=0..7, wm=w>>1 (4 m-quarters of 64 rows), wn=w&1 (2 n-halves of 64).

#define LDF(base, row, c0) \
    (*(const bf16x8*)&(base)[(row) * 64 + ((((c0) ^ ((row) & 7))) << 3)])

// 512 threads x 16B = 8KB per gload round; 2 rounds per 16KB slot, 6 total
__device__ __forceinline__ void stage3(const u16* a0, const u16* a1, const u16* b,
                                       u16* buf, int soff, int doff) {
    __builtin_amdgcn_global_load_lds(GLOBAL_AS(a0 + soff), LDS_AS(buf + doff), 16, 0, 0);
    __builtin_amdgcn_global_load_lds(GLOBAL_AS(a0 + 4096 + soff), LDS_AS(buf + 4096 + doff), 16, 0, 0);
    __builtin_amdgcn_global_load_lds(GLOBAL_AS(a1 + soff), LDS_AS(buf + TILE + doff), 16, 0, 0);
    __builtin_amdgcn_global_load_lds(GLOBAL_AS(a1 + 4096 + soff), LDS_AS(buf + TILE + 4096 + doff), 16, 0, 0);
    __builtin_amdgcn_global_load_lds(GLOBAL_AS(b + soff), LDS_AS(buf + 2 * TILE + doff), 16, 0, 0);
    __builtin_amdgcn_global_load_lds(GLOBAL_AS(b + 4096 + soff), LDS_AS(buf + 2 * TILE + 4096 + doff), 16, 0, 0);
}

__device__ __forceinline__ void compute_step(const u16* At, const u16* Bt,
                                             int arow, int brow,
                                             floatx4 (&acc)[4][4], int q, int li) {
#pragma unroll
    for (int s = 0; s < 2; ++s) {
        int c0 = s * 4 + q;
        bf16x8 bfr[4];
#pragma unroll
        for (int fn = 0; fn < 4; ++fn) bfr[fn] = LDF(Bt, brow + fn * 16 + li, c0);
#pragma unroll
        for (int fm = 0; fm < 4; ++fm) {
            bf16x8 af = LDF(At, arow + fm * 16 + li, c0);
#pragma unroll
            for (int fn = 0; fn < 4; ++fn)
                acc[fm][fn] = __builtin_amdgcn_mfma_f32_16x16x32_bf16(
                    af, bfr[fn], acc[fm][fn], 0, 0, 0);
        }
    }
}

// ---------------- pass A: h = relu(x @ W1 + b1), bf16 tiled out ----------------
// block tile 256m x 128n; grid = 8 experts x 16 n128-tiles x 5 m-slots = 640
__global__ __launch_bounds__(512) __attribute__((amdgpu_waves_per_eu(2)))
void gemm_a(const u16* __restrict__ At, const u16* __restrict__ Bt,
            const float* __restrict__ bias, u16* __restrict__ hsT,
            const int* __restrict__ cnt, const int* __restrict__ offs) {
    __shared__ u16 sm[2 * 3 * TILE];   // 96 KiB
    int bx = blockIdx.x;
    int e = bx & 7;
    int r = bx >> 3;
    int nt = r & 15;
    int mt0 = r >> 4;
    int count = cnt[e];
    int base128 = offs[e] >> 7;
    int tid = threadIdx.x;
    int w = tid >> 6, l = tid & 63, q = l >> 4, li = l & 15;
    int wm = w >> 1, wn = w & 1;
    int aslot = wm >> 1, arow = (wm & 1) * 64, brow = wn * 64;
    int soff = tid * 8, doff = w * 512;
#pragma unroll 1
    for (int mt = mt0; mt * 256 < count; mt += 5) {
        const u16* a0 = At + (size_t)((base128 + mt * 2 + 0) * 8) * TILE;
        const u16* a1 = At + (size_t)((base128 + mt * 2 + 1) * 8) * TILE;
        const u16* b0 = Bt + (size_t)((e * 16 + nt) * 8) * TILE;
        floatx4 acc[4][4];
#pragma unroll
        for (int a = 0; a < 4; ++a)
#pragma unroll
            for (int b = 0; b < 4; ++b) acc[a][b] = (floatx4)0.0f;

        // 2-phase pipeline: stage next K-tile, compute current, one sync per step
        stage3(a0, a1, b0, sm, soff, doff);
        __syncthreads();
        int cur = 0;
#pragma unroll 1
        for (int kt = 0; kt < 8; ++kt) {
            if (kt + 1 < 8)
                stage3(a0 + (kt + 1) * TILE, a1 + (kt + 1) * TILE, b0 + (kt + 1) * TILE,
                       sm + (cur ^ 1) * 3 * TILE, soff, doff);
            const u16* Atile = sm + (size_t)(cur * 3 + aslot) * TILE;
            const u16* Btile = sm + (size_t)(cur * 3 + 2) * TILE;
            compute_step(Atile, Btile, arow, brow, acc, q, li);
            __syncthreads();   // drains prefetch (vmcnt) AFTER compute: latency hidden
            cur ^= 1;
        }

        // epilogue: wave owns 64x64; swizzled image in private 8 KB LDS region,
        // then fully-contiguous dump (lane-16B reads, conflict-free)
        float bv[4];
#pragma unroll
        for (int fn = 0; fn < 4; ++fn)
            bv[fn] = bias[(size_t)e * DH + nt * 128 + wn * 64 + fn * 16 + li];
        u16* img = sm + (size_t)w * 4096;
#pragma unroll
        for (int fm = 0; fm < 4; ++fm)
#pragma unroll
            for (int fn = 0; fn < 4; ++fn)
#pragma unroll
                for (int rr = 0; rr < 4; ++rr) {
                    float v = acc[fm][fn][rr] + bv[fn];
                    v = v > 0.0f ? v : 0.0f;
                    int row = fm * 16 + q * 4 + rr;   // 0..63 (wave-local m)
                    int col = fn * 16 + li;           // 0..63 (k-local in hsT tile)
                    img[row * 64 + ((((col >> 3) ^ (row & 7)) << 3) | (col & 7))] = f2bf(v);
                }
        // own-region write->read within one wave: in-order DS + compiler lgkmcnt
        if ((mt * 2 + aslot) * 128 < count) {   // guard vs expert segment end
            u16* dst = hsT + ((size_t)(base128 + mt * 2 + aslot) * 32 + nt * 2 + wn) * TILE
                       + (wm & 1) * 4096;
#pragma unroll
            for (int j = 0; j < 8; ++j)
                *(ushort8*)&dst[j * 512 + l * 8] = *(const ushort8*)&img[j * 512 + l * 8];
        }
        __syncthreads();   // img regions reused as staging buffers next m-iter
    }
}

// ---------------- pass B: partial[ks] = h @ W2 over K-half, fp32 sorted layout ----------
// block tile 256m x 128n; grid = 8 experts x 4 n128 x 2 ks x 5 m-slots = 320
__global__ __launch_bounds__(512) __attribute__((amdgpu_waves_per_eu(2)))
void gemm_b(const u16* __restrict__ At, const u16* __restrict__ Bt,
            float* __restrict__ ps, const int* __restrict__ cnt,
            const int* __restrict__ offs) {
    __shared__ u16 sm[2 * 3 * TILE];   // 96 KiB
    int bx = blockIdx.x;
    int e = bx & 7;
    int r = bx >> 3;
    int nt = r & 3;
    int ks = (r >> 2) & 1;
    int mt0 = r >> 3;
    int count = cnt[e];
    int seg = offs[e];
    int base128 = seg >> 7;
    int tid = threadIdx.x;
    int w = tid >> 6, l = tid & 63, q = l >> 4, li = l & 15;
    int wm = w >> 1, wn = w & 1;
    int aslot = wm >> 1, arow = (wm & 1) * 64, brow = wn * 64;
    int soff = tid * 8, doff = w * 512;
#pragma unroll 1
    for (int mt = mt0; mt * 256 < count; mt += 5) {
        const u16* a0 = At + (size_t)((base128 + mt * 2 + 0) * 32 + ks * 16) * TILE;
        const u16* a1 = At + (size_t)((base128 + mt * 2 + 1) * 32 + ks * 16) * TILE;
        const u16* b0 = Bt + (size_t)((e * 4 + nt) * 32 + ks * 16) * TILE;
        floatx4 acc[4][4];
#pragma unroll
        for (int a = 0; a < 4; ++a)
#pragma unroll
            for (int b = 0; b < 4; ++b) acc[a][b] = (floatx4)0.0f;

        stage3(a0, a1, b0, sm, soff, doff);
        __syncthreads();
        int cur = 0;
#pragma unroll 1
        for (int kt = 0; kt < 16; ++kt) {
            if (kt + 1 < 16)
                stage3(a0 + (kt + 1) * TILE, a1 + (kt + 1) * TILE, b0 + (kt + 1) * TILE,
                       sm + (cur ^ 1) * 3 * TILE, soff, doff);
            const u16* Atile = sm + (size_t)(cur * 3 + aslot) * TILE;
            const u16* Btile = sm + (size_t)(cur * 3 + 2) * TILE;
            compute_step(Atile, Btile, arow, brow, acc, q, li);
            __syncthreads();
            cur ^= 1;
        }

        // direct fp32 stores; guard per 128-row half against segment overflow
        if ((mt * 2 + aslot) * 128 < count) {
            float* pbase = ps + ((size_t)ks * ROWCAP + seg + (size_t)mt * 256) * DOUT;
#pragma unroll
            for (int fn = 0; fn < 4; ++fn) {
                int col = nt * 128 + wn * 64 + fn * 16 + li;
#pragma unroll
                for (int fm = 0; fm < 4; ++fm) {
                    int row0 = wm * 64 + fm * 16 + q * 4;
#pragma unroll
                    for (int rr = 0; rr < 4; ++rr)
                        pbase[(size_t)(row0 + rr) * DOUT + col] = acc[fm][fn][rr];
                }
            }
        }
        // next iteration's stage3 targets LDS all waves stopped reading at the
        // final k-step barrier; no extra barrier needed
    }
}

// ---------------- reduce: out[i] = ps[0][rpos[i]] + ps[1][rpos[i]] + b2[groups[i]] ------
__global__ __launch_bounds__(256) void reduce_b(
        const float* __restrict__ ps, const int* __restrict__ rpos,
        const int* __restrict__ groups, const float* __restrict__ b2,
        float* __restrict__ out) {
    int idx = blockIdx.x * 256 + threadIdx.x;
    int i = idx >> 7;
    int c = (idx & 127) * 4;
    int pos = rpos[i];
    int g = groups[i];
    const float4 v0 = *(const float4*)&ps[(size_t)pos * DOUT + c];
    const float4 v1 = *(const float4*)&ps[((size_t)ROWCAP + pos) * DOUT + c];
    const float4 bb = *(const float4*)&b2[(size_t)g * DOUT + c];
    float4 o;
    o.x = v0.x + v1.x + bb.x; o.y = v0.y + v1.y + bb.y;
    o.z = v0.z + v1.z + bb.z; o.w = v0.w + v1.w + bb.w;
    *(float4*)&out[(size_t)i * DOUT + c] = o;
}

// ---------------- launch ----------------
extern "C" void kernel_launch(void* const* d_in, const int* in_sizes, int n_in,
                              void* d_out, int out_size, void* d_ws, size_t ws_size,
                              hipStream_t stream) {
    const float* x = (const float*)d_in[0];
    const int* groups = (const int*)d_in[1];
    const float* W1 = (const float*)d_in[2];
    const float* b1 = (const float*)d_in[3];
    const float* W2 = (const float*)d_in[4];
    const float* b2 = (const float*)d_in[5];
    float* out = (float*)d_out;

    char* ws = (char*)d_ws;
    size_t o = 0;
    auto alloc = [&](size_t bytes) {
        void* p = ws + o;
        o = (o + bytes + 255) & ~(size_t)255;
        return p;
    };
    int* cnt = (int*)alloc(NEXP * 4);
    int* offs = (int*)alloc(NEXP * 4);
    int* perm = (int*)alloc((size_t)ROWCAP * 4);
    int* rpos = (int*)alloc((size_t)NB * 4);
    u16* xsT = (u16*)alloc((size_t)(RCAPRD / 128) * 8 * TILE * 2);    // ~10.5 MB (read-pad)
    u16* w1tT = (u16*)alloc((size_t)NEXP * DIN * DH * 2);             // 16.8 MB
    u16* w2tT = (u16*)alloc((size_t)NEXP * DH * DOUT * 2);            // 16.8 MB
    u16* hsT = (u16*)alloc((size_t)(RCAPRD / 128) * 32 * TILE * 2);   // ~41.9 MB (read-pad)
    float* ps = (float*)alloc((size_t)2 * ROWCAP * DOUT * 4);         // ~37.7 MB

    route_kernel<<<1, 256, 0, stream>>>(groups, cnt, offs, perm, rpos);
    prep_kernel<<<6144, 256, 0, stream>>>(x, W1, W2, rpos, xsT, w1tT, w2tT);
    gemm_a<<<NEXP * 16 * 5, 512, 0, stream>>>(xsT, w1tT, b1, hsT, cnt, offs);
    gemm_b<<<NEXP * 4 * 2 * 5, 512, 0, stream>>>(hsT, w2tT, ps, cnt, offs);
    reduce_b<<<(NB * (DOUT / 4)) / 256, 256, 0, stream>>>(ps, rpos, groups, b2, out);
}